// Round 1
// 261.139 us; speedup vs baseline: 1.1276x; 1.1276x over previous
//
#include <hip/hip_runtime.h>

// Problem constants (B,S,D,H,HD) = (4,1024,1024,16,64)
#define B_ 4
#define S_ 1024
#define D_ 1024
#define H_ 16
#define E_ 64
#define BS_ (B_*S_)
#define BHSE_ (B_*H_*S_*E_)   // 4,194,304

typedef __attribute__((ext_vector_type(8))) short bf16x8;   // 8 bf16 in 4 VGPRs
typedef __attribute__((ext_vector_type(4))) float f32x4;

__device__ __forceinline__ unsigned short f2bf(float f) {
    unsigned int x = __float_as_uint(f);
    x = (x + 0x7FFFu + ((x >> 16) & 1u)) >> 16;   // RNE
    return (unsigned short)x;
}
__device__ __forceinline__ float bf2f(unsigned short u) {
    return __uint_as_float(((unsigned int)u) << 16);
}
__device__ __forceinline__ float ldin(const void* p, size_t i, int isb) {
    return isb ? bf2f(((const unsigned short*)p)[i]) : ((const float*)p)[i];
}

// 2^x : v_exp_f32 is natively base-2
#if __has_builtin(__builtin_amdgcn_exp2f)
#define EXP2(x) __builtin_amdgcn_exp2f(x)
#else
#define EXP2(x) __expf((x) * 0.6931471805599453f)
#endif

// async global->LDS, 16B per lane; LDS dest = wave-uniform base + lane*16
__device__ __forceinline__ void gl2lds16(const void* g, void* l) {
    __builtin_amdgcn_global_load_lds(
        (const __attribute__((address_space(1))) void*)g,
        (__attribute__((address_space(3))) void*)l, 16, 0, 0);
}

// ---------------------------------------------------------------------------
// Kernel 0: detect input dtype (1=bf16, 0=fp32).
// ---------------------------------------------------------------------------
__global__ void detect_dtype(const unsigned int* q, int* flag) {
    __shared__ int cnt;
    if (threadIdx.x == 0) cnt = 0;
    __syncthreads();
    unsigned int w = q[threadIdx.x];
    unsigned int lo = w & 0xFFFFu;
    unsigned int e = (lo >> 7) & 0xFFu;
    int ok = (lo == 0u) || (e >= 100u && e <= 145u);
    atomicAdd(&cnt, ok);
    __syncthreads();
    if (threadIdx.x == 0) flag[0] = (cnt >= 240) ? 1 : 0;
}

// ---------------------------------------------------------------------------
// Kernel 1: weight permutes via LDS-transposed 64x64 tiles (both directions
// coalesced). z=0..2: W{q,k,v}[h][d][e] -> WT[z][(h*64+e)][d];
// z=3: Wo[d][o] -> WT[3][o][d].
// ---------------------------------------------------------------------------
__global__ __launch_bounds__(256) void conv_w2(
        const void* Wq, const void* Wk, const void* Wv, const void* Wo,
        const void* bq_, const void* bk_, const void* bv_, const void* bo_,
        unsigned short* WT, float* biases, const int* flag) {
    __shared__ unsigned short Tt[64][72];
    const int isb = flag[0];
    const int z = blockIdx.z, t = threadIdx.x;
    const void* src = (z == 0) ? Wq : (z == 1) ? Wk : (z == 2) ? Wv : Wo;
    const int r0 = blockIdx.y * 64;          // d-tile origin
    const int c0 = blockIdx.x;               // head (z<3) or o-tile (z=3)
    {
        int dl = t >> 2, qc = t & 3;
        size_t base;
        if (z < 3) base = (size_t)c0 * 65536 + (size_t)(r0 + dl) * 64 + qc * 16;
        else       base = (size_t)(r0 + dl) * 1024 + (size_t)c0 * 64 + qc * 16;
        if (isb) {
            const unsigned short* s = (const unsigned short*)src + base;
            bf16x8 a0 = *(const bf16x8*)s, a1 = *(const bf16x8*)(s + 8);
#pragma unroll
            for (int j = 0; j < 8; j++) {
                Tt[qc * 16 + j][dl] = (unsigned short)a0[j];
                Tt[qc * 16 + 8 + j][dl] = (unsigned short)a1[j];
            }
        } else {
            const float* s = (const float*)src + base;
#pragma unroll
            for (int j = 0; j < 16; j++) Tt[qc * 16 + j][dl] = f2bf(s[j]);
        }
    }
    __syncthreads();
    {
        int el = t >> 2, qc = t & 3;
        size_t dst = (size_t)z * D_ * D_ + (size_t)(c0 * 64 + el) * D_ + r0 + qc * 16;
        *(bf16x8*)&WT[dst]     = *(const bf16x8*)&Tt[el][qc * 16];
        *(bf16x8*)&WT[dst + 8] = *(const bf16x8*)&Tt[el][qc * 16 + 8];
    }
    if (z == 3 && blockIdx.y == 0 && blockIdx.x < 4) {
        const void* bs = (blockIdx.x == 0) ? bq_ : (blockIdx.x == 1) ? bk_
                       : (blockIdx.x == 2) ? bv_ : bo_;
#pragma unroll
        for (int j = 0; j < 4; j++) {
            int i = t * 4 + j;
            biases[blockIdx.x * 1024 + i] = ldin(bs, i, isb);
        }
    }
}

// ---------------------------------------------------------------------------
// Kernel 2: mask bitpack, transposed: packT[b][kt][s] bit k = mask[b][s][kt*64+k]
// ---------------------------------------------------------------------------
__global__ void maskpack(const int* mask, unsigned long long* packT) {
    int W = blockIdx.x * 4 + (threadIdx.x >> 6);    // 0..65535
    int lane = threadIdx.x & 63;
    int b = W >> 14, rem = W & 16383, s = rem >> 4, kt = rem & 15;
    int mv = mask[((size_t)b * 1024 + s) * 1024 + kt * 64 + lane];
    unsigned long long bits = __ballot(mv != 0);
    if (lane == 0) packT[((size_t)b * 16 + kt) * 1024 + s] = bits;
}

// ---------------------------------------------------------------------------
// Kernel 2b (R9 NEW): one-shot fp32 -> bf16 conversion of q,k,v inputs.
// Rationale: the proj GEMM re-reads A 16x (once per n-tile); converting once
// here (a) halves every re-read's bytes, (b) removes the per-tile VALU
// convert from the GEMM staging path, (c) lets the GEMM use pure
// global_load_lds DMA. Skipped entirely when inputs are already bf16.
// 72 MB of traffic -> ~12-15 us.
// ---------------------------------------------------------------------------
__global__ __launch_bounds__(256) void conv_a(
        const float* q, const float* k, const float* v,
        unsigned short* dst, const int* flag) {
    if (flag[0]) return;                       // inputs already bf16
    const int z = blockIdx.x >> 11;            // 2048 blocks per tensor
    const float* s = (z == 0) ? q : (z == 1) ? k : v;
    const size_t i = ((size_t)(blockIdx.x & 2047) * 256 + threadIdx.x) * 8;
    f32x4 a0 = *(const f32x4*)(s + i);
    f32x4 a1 = *(const f32x4*)(s + i + 4);
    bf16x8 o;
#pragma unroll
    for (int j = 0; j < 4; j++) {
        o[j]     = (short)f2bf(a0[j]);
        o[4 + j] = (short)f2bf(a1[j]);
    }
    *(bf16x8*)&dst[(size_t)z * ((size_t)BS_ * D_) + i] = o;
}

// ---------------------------------------------------------------------------
// Kernel 3 (R9): bf16 MFMA GEMM. R8 internals kept (DMA dbuf, one
// barrier/iter, XOR-4 swizzle). CHANGED:
//  (1) A is ALWAYS bf16 now (inputs pre-converted by conv_a when fp32), so
//      staging is pure global_load_lds — no VALU on the staging path;
//  (2) MODE 0 grid remap is XCD-aware: hardware round-robins dispatch id
//      mod 8 across XCDs, so we give XCD x the m-tile stripe [4x,4x+4) for
//      all (n,z). Per-XCD A slice = 3 MB bf16 -> L2-resident; the 16x A
//      reuse across n-tiles becomes L2 hits instead of HBM/L3 re-fetches.
//  (3) K-phase rotation keyed on (n,z) only, so the 4 blocks in an XCD that
//      share a B tile (same n,z, different m) walk K in lockstep -> B
//      granules get their 4x in-XCD reuse inside a tight window; A reuse
//      (across n, decorrelated phases) is covered by L2 residency.
// MODE 0: 3 projections (z: Q,K -> [b][h][s][e]; V -> [b][h][e][s]).
// MODE 1: final GEMM (A=heads bf16), writes d_out per dtype flag.
// ---------------------------------------------------------------------------
template<int BM, int BN, int MODE, int MINW>
__global__ __launch_bounds__(256, MINW) void gemm_k(
        const void* A0, const void* A1, const void* A2, const unsigned short* Aconv,
        const unsigned short* BtB, const float* biasB, void* dstB, const int* flag) {
    constexpr int TOT16 = (BM + BN) * 32;       // ushorts per buffer
    constexpr int CALLS = TOT16 / 512;          // 1KB chunks (16 rows x 32 cols)
    constexpr int CPW = CALLS / 4;
    constexpr int MT = BM / 32;                 // wave-tile (BM/2)x(BN/2)
    constexpr int NT = BN / 32;
    __shared__ unsigned short buf[2][TOT16];

    const int t = threadIdx.x, lane = t & 63, w = t >> 6;
    const int lm = lane & 15, q4 = lane >> 4;
    const int wm = w >> 1, wn = w & 1;
    const int lr = lane >> 2;                    // row-in-chunk 0..15
    const int ls = lane & 3;                     // LDS slot 0..3
    const int lg = ls ^ ((lr >> 1) & 3);         // source granule (swizzle)
    const int fl = flag[0];

    const unsigned short* Abf;
    const unsigned short* Bt;
    const float* bias;
    int z = 0, m0, n0, phase;
    if (MODE == 0) {
        // grid is (32,16,3); dispatch id -> XCD = id & 7 (round-robin)
        int bid = blockIdx.x + (blockIdx.y << 5) + (blockIdx.z << 9);
        int xcd = bid & 7, idx = bid >> 3;       // idx 0..191 within XCD
        z = idx >> 6;                            // 0..2
        int r = idx & 63;
        int mt = (xcd << 2) + (r & 3);           // XCD x owns m-tiles 4x..4x+3
        int nt = r >> 2;                         // 0..15
        m0 = mt * BM; n0 = nt * BN;
        phase = (nt * 13 + z * 5) & 31;          // same-B blocks K-aligned
        const void* Ain = (z == 0) ? A0 : (z == 1 ? A1 : A2);
        Abf = fl ? (const unsigned short*)Ain
                 : Aconv + (size_t)z * ((size_t)BS_ * D_);
        Bt = BtB + (size_t)z * D_ * D_;
        bias = biasB + z * 1024;
    } else {
        Abf = (const unsigned short*)A0;         // heads, always bf16
        Bt = BtB; bias = biasB;
        m0 = blockIdx.x * BM; n0 = blockIdx.y * BN;
        phase = (blockIdx.x * 7 + blockIdx.y * 13) & 31;
    }

    // stage K-slice kk into buffer bi (swizzled: slot s of row r holds
    // global granule s ^ ((r>>1)&3)) — pure DMA, A and B both bf16
    auto stage = [&](int kk, int bi) {
#pragma unroll
        for (int i = 0; i < CPW; ++i) {
            int c = w * CPW + i;
            int row = c * 16 + lr;
            const unsigned short* g;
            if (row < BM)
                g = Abf + (size_t)(m0 + row) * D_ + kk + lg * 8;
            else
                g = Bt + (size_t)(n0 + row - BM) * D_ + kk + lg * 8;
            gl2lds16(g, &buf[bi][c * 512]);
        }
    };

    f32x4 acc[MT][NT];
#pragma unroll
    for (int i = 0; i < MT; i++)
#pragma unroll
        for (int j = 0; j < NT; j++) acc[i][j] = (f32x4){0.f, 0.f, 0.f, 0.f};

    stage((phase & 31) * 32, 0);
    for (int it = 0; it < D_ / 32; ++it) {
        const int bi = it & 1;
        __syncthreads();                 // drains the prefetch of slice `it`
        if (it < D_ / 32 - 1) stage(((it + 1 + phase) & 31) * 32, bi ^ 1);

        const unsigned short* As = buf[bi];
        const unsigned short* Bs = buf[bi] + BM * 32;
        bf16x8 af[MT], bv[NT];
#pragma unroll
        for (int mt = 0; mt < MT; mt++) {
            int row = wm * (BM / 2) + mt * 16 + lm;
            af[mt] = *(const bf16x8*)&As[row * 32 + (q4 ^ ((row >> 1) & 3)) * 8];
        }
#pragma unroll
        for (int nt = 0; nt < NT; nt++) {
            int row = wn * (BN / 2) + nt * 16 + lm;
            bv[nt] = *(const bf16x8*)&Bs[row * 32 + (q4 ^ ((row >> 1) & 3)) * 8];
        }
#pragma unroll
        for (int mt = 0; mt < MT; mt++)
#pragma unroll
            for (int nt = 0; nt < NT; nt++)
                acc[mt][nt] = __builtin_amdgcn_mfma_f32_16x16x32_bf16(
                    af[mt], bv[nt], acc[mt][nt], 0, 0, 0);
    }

    // epilogue: C/D layout col=lane&15, row=(lane>>4)*4+reg
#pragma unroll
    for (int mt = 0; mt < MT; mt++)
#pragma unroll
        for (int nt = 0; nt < NT; nt++) {
            int N = n0 + wn * (BN / 2) + nt * 16 + lm;
            int Mb = m0 + wm * (BM / 2) + mt * 16 + q4 * 4;
            if (MODE == 0 && z == 2) {
                // V^T: 4 consecutive s per lane -> one b64 store
                int bb = Mb >> 10, sb = Mb & 1023, hh = N >> 6, e = N & 63;
                unsigned long long hv = 0;
#pragma unroll
                for (int r = 0; r < 4; r++)
                    hv |= (unsigned long long)f2bf(acc[mt][nt][r] + bias[N]) << (16 * r);
                unsigned short* d16 = (unsigned short*)dstB + (size_t)2 * BHSE_;
                *(unsigned long long*)&d16[(((size_t)(bb * H_ + hh) * E_ + e) << 10) + sb] = hv;
            } else {
#pragma unroll
                for (int r = 0; r < 4; r++) {
                    int M = Mb + r;
                    float v = acc[mt][nt][r] + bias[N];
                    if (MODE == 0) {
                        int bb = M >> 10, s = M & 1023, hh = N >> 6, e = N & 63;
                        unsigned short* d16 = (unsigned short*)dstB + (size_t)z * BHSE_;
                        d16[((size_t)(bb * H_ + hh) * S_ + s) * E_ + e] = f2bf(v);
                    } else {
                        size_t idx = (size_t)M * D_ + N;
                        if (fl) ((unsigned short*)dstB)[idx] = f2bf(v);
                        else    ((float*)dstB)[idx] = v;
                    }
                }
            }
        }
}

// ---------------------------------------------------------------------------
// Kernel 4: fused attention — unchanged from R8 (3-D grid, LDS
// double-buffered K/V DMA tiles, XOR swizzle, base-2 softmax).
// ---------------------------------------------------------------------------
#define PSTR 88
__global__ __launch_bounds__(256) void attn64(
        const unsigned short* Qp, const unsigned short* Kp, const unsigned short* VpT,
        const unsigned long long* packT, unsigned short* heads) {
    __shared__ unsigned short KT[2][4096];   // [buf][64 keys x 64 e], swizzled
    __shared__ unsigned short VT[2][4096];   // [buf][64 e x 64 keys], swizzled
    __shared__ unsigned short Pw[4][16 * PSTR];

    const int qt = blockIdx.x, h = blockIdx.y, b = blockIdx.z;
    const int t = threadIdx.x, w = t >> 6, lane = t & 63, lm = lane & 15, q4 = lane >> 4;
    const size_t bh = ((size_t)b * H_ + h) * S_ * E_;
    const unsigned short* Qb = Qp + bh;
    const unsigned short* Kb = Kp + bh;
    const unsigned short* Vb = VpT + bh;                // Vb[e*1024 + s]
    const int q0 = qt * 64 + w * 16;
    unsigned short* P = &Pw[w][0];

    // per-lane invariant DMA source offsets (ushort units)
    const int l3 = lane >> 3, l7 = lane & 7;
    const int kLaneOff = l3 * 64 + (l7 ^ l3) * 8;       // within an 8-row K chunk
    const int vLaneOff = l3 * 1024 + (l7 ^ l3) * 8;     // within an 8-row V chunk

    // swizzled LDS fragment chunk indices (granule = 8 ushorts)
    const int sw = lm & 7;
    const int c0 = (q4 ^ sw) * 8, c1 = ((q4 ^ 4) ^ sw) * 8;

    // Q B-fragments, held for the whole sweep
    bf16x8 bq0 = *(const bf16x8*)&Qb[(size_t)(q0 + lm) * E_ + q4 * 8];
    bf16x8 bq1 = *(const bf16x8*)&Qb[(size_t)(q0 + lm) * E_ + 32 + q4 * 8];

    f32x4 oacc[4];
#pragma unroll
    for (int i = 0; i < 4; i++) oacc[i] = (f32x4){0.f, 0.f, 0.f, 0.f};
    float mrun = -3.0e38f, lrun = 0.f;
    const float scale2 = 0.03125f * 1.4426950408889634f;   // log2e / sqrt(D)

#define STAGE(ktile, bufi)                                                    \
    {                                                                         \
        int k0s = (ktile) * 64;                                               \
        _Pragma("unroll")                                                     \
        for (int i_ = 0; i_ < 4; ++i_) {                                      \
            int c_ = w * 4 + i_;                                              \
            if (c_ < 8) {                                                     \
                gl2lds16(Kb + (size_t)k0s * 64 + c_ * 512 + kLaneOff,         \
                         &KT[bufi][c_ * 512]);                                \
            } else {                                                          \
                int cc_ = c_ - 8;                                             \
                gl2lds16(Vb + (size_t)cc_ * 8192 + k0s + vLaneOff,            \
                         &VT[bufi][cc_ * 512]);                               \
            }                                                                 \
        }                                                                     \
    }

    STAGE(0, 0)

    for (int kt = 0; kt < S_ / 64; ++kt) {
        const int bufi = kt & 1;
        __syncthreads();                 // own-vmcnt drain + barrier: tile kt ready
        if (kt < 15) STAGE(kt + 1, bufi ^ 1)

        unsigned long long mk = packT[((size_t)b * 16 + kt) * 1024 + q0 + lm];

        // Sc^T from LDS K tile
        f32x4 st[4];
#pragma unroll
        for (int jt = 0; jt < 4; ++jt) {
            const unsigned short* kr = &KT[bufi][(jt * 16 + lm) * 64];
            bf16x8 ka0 = *(const bf16x8*)&kr[c0];
            bf16x8 ka1 = *(const bf16x8*)&kr[c1];
            f32x4 zz = (f32x4){0.f, 0.f, 0.f, 0.f};
            zz = __builtin_amdgcn_mfma_f32_16x16x32_bf16(ka0, bq0, zz, 0, 0, 0);
            zz = __builtin_amdgcn_mfma_f32_16x16x32_bf16(ka1, bq1, zz, 0, 0, 0);
            st[jt] = zz;
        }
        float sv[4][4];
        float tmx = -3.0e38f;
#pragma unroll
        for (int jt = 0; jt < 4; ++jt)
#pragma unroll
            for (int r = 0; r < 4; r++) {
                int kb = jt * 16 + q4 * 4 + r;
                float xm = ((mk >> kb) & 1ull) ? st[jt][r] * scale2 : -3.0e38f;
                sv[jt][r] = xm;
                tmx = fmaxf(tmx, xm);
            }
        tmx = fmaxf(tmx, __shfl_xor(tmx, 16, 64));
        tmx = fmaxf(tmx, __shfl_xor(tmx, 32, 64));
        float mnew = fmaxf(mrun, tmx);
        float alpha = EXP2(mrun - mnew);
        float ssum = 0.f;
        unsigned long long pk[4];
#pragma unroll
        for (int jt = 0; jt < 4; ++jt) {
            float p0 = EXP2(sv[jt][0] - mnew);
            float p1 = EXP2(sv[jt][1] - mnew);
            float p2 = EXP2(sv[jt][2] - mnew);
            float p3 = EXP2(sv[jt][3] - mnew);
            ssum += (p0 + p1) + (p2 + p3);
            pk[jt] = (unsigned long long)f2bf(p0)
                   | ((unsigned long long)f2bf(p1) << 16)
                   | ((unsigned long long)f2bf(p2) << 32)
                   | ((unsigned long long)f2bf(p3) << 48);
        }
        ssum += __shfl_xor(ssum, 16, 64);
        ssum += __shfl_xor(ssum, 32, 64);
        lrun = lrun * alpha + ssum;
        mrun = mnew;
#pragma unroll
        for (int nt = 0; nt < 4; nt++) oacc[nt] = oacc[nt] * alpha;

        // P C->B layout via per-wave LDS (in-order DS pipe, no barrier)
#pragma unroll
        for (int jt = 0; jt < 4; ++jt)
            *(unsigned long long*)&P[lm * PSTR + jt * 16 + q4 * 4] = pk[jt];
        bf16x8 bp0 = *(const bf16x8*)&P[lm * PSTR + q4 * 8];
        bf16x8 bp1 = *(const bf16x8*)&P[lm * PSTR + 32 + q4 * 8];

        // PV from LDS V tile
#pragma unroll
        for (int nt = 0; nt < 4; nt++) {
            const unsigned short* vr = &VT[bufi][(nt * 16 + lm) * 64];
            bf16x8 va0 = *(const bf16x8*)&vr[c0];
            bf16x8 va1 = *(const bf16x8*)&vr[c1];
            oacc[nt] = __builtin_amdgcn_mfma_f32_16x16x32_bf16(va0, bp0, oacc[nt], 0, 0, 0);
            oacc[nt] = __builtin_amdgcn_mfma_f32_16x16x32_bf16(va1, bp1, oacc[nt], 0, 0, 0);
        }
    }

    float inv = 1.0f / lrun;
#pragma unroll
    for (int nt = 0; nt < 4; nt++) {
        unsigned long long hv =
              (unsigned long long)f2bf(oacc[nt][0] * inv)
            | ((unsigned long long)f2bf(oacc[nt][1] * inv) << 16)
            | ((unsigned long long)f2bf(oacc[nt][2] * inv) << 32)
            | ((unsigned long long)f2bf(oacc[nt][3] * inv) << 48);
        *(unsigned long long*)&heads[(size_t)(b * S_ + q0 + lm) * D_ + h * E_ + nt * 16 + q4 * 4] = hv;
    }
}

// ---------------------------------------------------------------------------
extern "C" void kernel_launch(void* const* d_in, const int* in_sizes, int n_in,
                              void* d_out, int out_size, void* d_ws, size_t ws_size,
                              hipStream_t stream) {
    char* ws = (char*)d_ws;
    int* flag = (int*)ws;
    unsigned short* WT = (unsigned short*)(ws + 256);    // [4][1024][1024] bf16
    unsigned short* WqT = WT;
    unsigned short* WoT = WT + (size_t)3 * D_ * D_;
    float* biases = (float*)(WT + (size_t)4 * D_ * D_);  // [4][1024]
    float* bq = biases;
    float* bo = biases + 3 * 1024;
    unsigned short* Qp = (unsigned short*)(biases + 4 * 1024);  // [b][h][s][e]
    unsigned short* Kp = Qp + (size_t)BHSE_;                    // [b][h][s][e]
    unsigned short* Vp = Kp + (size_t)BHSE_;                    // [b][h][e][s]
    unsigned short* heads = Vp + (size_t)BHSE_;                 // [b*s][h*64+e]
    unsigned long long* packT = (unsigned long long*)(heads + (size_t)BHSE_);
    unsigned short* Aconv = (unsigned short*)(packT + (size_t)B_ * 16 * S_); // [3][4096][1024] bf16

    detect_dtype<<<1, 256, 0, stream>>>((const unsigned int*)d_in[0], flag);
    conv_w2<<<dim3(16, 16, 4), 256, 0, stream>>>(
        d_in[4], d_in[6], d_in[8], d_in[10],
        d_in[5], d_in[7], d_in[9], d_in[11], WT, biases, flag);
    maskpack<<<16384, 256, 0, stream>>>((const int*)d_in[3], packT);
    // one-shot fp32->bf16 A conversion (no-op when inputs already bf16)
    conv_a<<<6144, 256, 0, stream>>>(
        (const float*)d_in[0], (const float*)d_in[1], (const float*)d_in[2],
        Aconv, flag);
    // proj: 128x64 tiles -> 32 x 16 x 3 = 1536 blocks (6/CU), XCD m-stripes
    gemm_k<128, 64, 0, 4><<<dim3(32, 16, 3), 256, 0, stream>>>(
        d_in[0], d_in[1], d_in[2], Aconv, WqT, bq, Qp, flag);
    attn64<<<dim3(16, 16, 4), 256, 0, stream>>>(Qp, Kp, Vp, packT, heads);
    // final: 64x64 tiles -> 64 x 16 = 1024 blocks (4/CU), VGPR<=64 forced
    gemm_k<64, 64, 1, 8><<<dim3(64, 16, 1), 256, 0, stream>>>(
        heads, nullptr, nullptr, nullptr, WoT, bo, d_out, flag);
}

// Round 2
// 251.699 us; speedup vs baseline: 1.1699x; 1.0375x over previous
//
#include <hip/hip_runtime.h>

// Problem constants (B,S,D,H,HD) = (4,1024,1024,16,64)
#define B_ 4
#define S_ 1024
#define D_ 1024
#define H_ 16
#define E_ 64
#define BS_ (B_*S_)
#define BHSE_ (B_*H_*S_*E_)   // 4,194,304

typedef __attribute__((ext_vector_type(8))) short bf16x8;   // 8 bf16 in 4 VGPRs
typedef __attribute__((ext_vector_type(4))) float f32x4;
typedef __attribute__((ext_vector_type(4))) unsigned int u32x4;

__device__ __forceinline__ unsigned short f2bf(float f) {
    unsigned int x = __float_as_uint(f);
    x = (x + 0x7FFFu + ((x >> 16) & 1u)) >> 16;   // RNE
    return (unsigned short)x;
}
__device__ __forceinline__ float bf2f(unsigned short u) {
    return __uint_as_float(((unsigned int)u) << 16);
}
__device__ __forceinline__ float ldin(const void* p, size_t i, int isb) {
    return isb ? bf2f(((const unsigned short*)p)[i]) : ((const float*)p)[i];
}

// 2 f32 -> packed 2xbf16 in one VALU op (RNE) — no builtin on gfx950, asm it
__device__ __forceinline__ unsigned int cvtpk(float lo, float hi) {
    unsigned int r;
    asm("v_cvt_pk_bf16_f32 %0, %1, %2" : "=v"(r) : "v"(lo), "v"(hi));
    return r;
}
__device__ __forceinline__ unsigned int bperm(int srclane4, unsigned int v) {
    return (unsigned int)__builtin_amdgcn_ds_bpermute(srclane4, (int)v);
}
__device__ __forceinline__ bf16x8 u4bf(u32x4 w) {
    union { u32x4 u; bf16x8 h; } c; c.u = w; return c.h;
}

// 2^x : v_exp_f32 is natively base-2
#if __has_builtin(__builtin_amdgcn_exp2f)
#define EXP2(x) __builtin_amdgcn_exp2f(x)
#else
#define EXP2(x) __expf((x) * 0.6931471805599453f)
#endif

// async global->LDS, 16B per lane; LDS dest = wave-uniform base + lane*16
__device__ __forceinline__ void gl2lds16(const void* g, void* l) {
    __builtin_amdgcn_global_load_lds(
        (const __attribute__((address_space(1))) void*)g,
        (__attribute__((address_space(3))) void*)l, 16, 0, 0);
}

// ---------------------------------------------------------------------------
// Kernel 0: detect input dtype (1=bf16, 0=fp32).
// ---------------------------------------------------------------------------
__global__ void detect_dtype(const unsigned int* q, int* flag) {
    __shared__ int cnt;
    if (threadIdx.x == 0) cnt = 0;
    __syncthreads();
    unsigned int w = q[threadIdx.x];
    unsigned int lo = w & 0xFFFFu;
    unsigned int e = (lo >> 7) & 0xFFu;
    int ok = (lo == 0u) || (e >= 100u && e <= 145u);
    atomicAdd(&cnt, ok);
    __syncthreads();
    if (threadIdx.x == 0) flag[0] = (cnt >= 240) ? 1 : 0;
}

// ---------------------------------------------------------------------------
// Kernel 1: weight permutes via LDS-transposed 64x64 tiles (both directions
// coalesced). z=0..2: W{q,k,v}[h][d][e] -> WT[z][(h*64+e)][d];
// z=3: Wo[d][o] -> WT[3][o][d].
// ---------------------------------------------------------------------------
__global__ __launch_bounds__(256) void conv_w2(
        const void* Wq, const void* Wk, const void* Wv, const void* Wo,
        const void* bq_, const void* bk_, const void* bv_, const void* bo_,
        unsigned short* WT, float* biases, const int* flag) {
    __shared__ unsigned short Tt[64][72];
    const int isb = flag[0];
    const int z = blockIdx.z, t = threadIdx.x;
    const void* src = (z == 0) ? Wq : (z == 1) ? Wk : (z == 2) ? Wv : Wo;
    const int r0 = blockIdx.y * 64;          // d-tile origin
    const int c0 = blockIdx.x;               // head (z<3) or o-tile (z=3)
    {
        int dl = t >> 2, qc = t & 3;
        size_t base;
        if (z < 3) base = (size_t)c0 * 65536 + (size_t)(r0 + dl) * 64 + qc * 16;
        else       base = (size_t)(r0 + dl) * 1024 + (size_t)c0 * 64 + qc * 16;
        if (isb) {
            const unsigned short* s = (const unsigned short*)src + base;
            bf16x8 a0 = *(const bf16x8*)s, a1 = *(const bf16x8*)(s + 8);
#pragma unroll
            for (int j = 0; j < 8; j++) {
                Tt[qc * 16 + j][dl] = (unsigned short)a0[j];
                Tt[qc * 16 + 8 + j][dl] = (unsigned short)a1[j];
            }
        } else {
            const float* s = (const float*)src + base;
#pragma unroll
            for (int j = 0; j < 16; j++) Tt[qc * 16 + j][dl] = f2bf(s[j]);
        }
    }
    __syncthreads();
    {
        int el = t >> 2, qc = t & 3;
        size_t dst = (size_t)z * D_ * D_ + (size_t)(c0 * 64 + el) * D_ + r0 + qc * 16;
        *(bf16x8*)&WT[dst]     = *(const bf16x8*)&Tt[el][qc * 16];
        *(bf16x8*)&WT[dst + 8] = *(const bf16x8*)&Tt[el][qc * 16 + 8];
    }
    if (z == 3 && blockIdx.y == 0 && blockIdx.x < 4) {
        const void* bs = (blockIdx.x == 0) ? bq_ : (blockIdx.x == 1) ? bk_
                       : (blockIdx.x == 2) ? bv_ : bo_;
#pragma unroll
        for (int j = 0; j < 4; j++) {
            int i = t * 4 + j;
            biases[blockIdx.x * 1024 + i] = ldin(bs, i, isb);
        }
    }
}

// ---------------------------------------------------------------------------
// Kernel 2: mask bitpack, transposed: packT[b][kt][s] bit k = mask[b][s][kt*64+k]
// ---------------------------------------------------------------------------
__global__ void maskpack(const int* mask, unsigned long long* packT) {
    int W = blockIdx.x * 4 + (threadIdx.x >> 6);    // 0..65535
    int lane = threadIdx.x & 63;
    int b = W >> 14, rem = W & 16383, s = rem >> 4, kt = rem & 15;
    int mv = mask[((size_t)b * 1024 + s) * 1024 + kt * 64 + lane];
    unsigned long long bits = __ballot(mv != 0);
    if (lane == 0) packT[((size_t)b * 16 + kt) * 1024 + s] = bits;
}

// ---------------------------------------------------------------------------
// Kernel 2b: one-shot fp32 -> bf16 conversion of q,k,v inputs.
// ---------------------------------------------------------------------------
__global__ __launch_bounds__(256) void conv_a(
        const float* q, const float* k, const float* v,
        unsigned short* dst, const int* flag) {
    if (flag[0]) return;                       // inputs already bf16
    const int z = blockIdx.x >> 11;            // 2048 blocks per tensor
    const float* s = (z == 0) ? q : (z == 1) ? k : v;
    const size_t i = ((size_t)(blockIdx.x & 2047) * 256 + threadIdx.x) * 8;
    f32x4 a0 = *(const f32x4*)(s + i);
    f32x4 a1 = *(const f32x4*)(s + i + 4);
    bf16x8 o;
#pragma unroll
    for (int j = 0; j < 4; j++) {
        o[j]     = (short)f2bf(a0[j]);
        o[4 + j] = (short)f2bf(a1[j]);
    }
    *(bf16x8*)&dst[(size_t)z * ((size_t)BS_ * D_) + i] = o;
}

// ---------------------------------------------------------------------------
// Kernel 3: bf16 MFMA GEMM (unchanged from R9: DMA dbuf, one barrier/iter,
// XOR-4 swizzle, XCD m-stripes for MODE 0).
// MODE 0: 3 projections (z: Q,K -> [b][h][s][e]; V -> [b][h][e][s]).
// MODE 1: final GEMM (A=heads bf16), writes d_out per dtype flag.
// ---------------------------------------------------------------------------
template<int BM, int BN, int MODE, int MINW>
__global__ __launch_bounds__(256, MINW) void gemm_k(
        const void* A0, const void* A1, const void* A2, const unsigned short* Aconv,
        const unsigned short* BtB, const float* biasB, void* dstB, const int* flag) {
    constexpr int TOT16 = (BM + BN) * 32;       // ushorts per buffer
    constexpr int CALLS = TOT16 / 512;          // 1KB chunks (16 rows x 32 cols)
    constexpr int CPW = CALLS / 4;
    constexpr int MT = BM / 32;                 // wave-tile (BM/2)x(BN/2)
    constexpr int NT = BN / 32;
    __shared__ unsigned short buf[2][TOT16];

    const int t = threadIdx.x, lane = t & 63, w = t >> 6;
    const int lm = lane & 15, q4 = lane >> 4;
    const int wm = w >> 1, wn = w & 1;
    const int lr = lane >> 2;                    // row-in-chunk 0..15
    const int ls = lane & 3;                     // LDS slot 0..3
    const int lg = ls ^ ((lr >> 1) & 3);         // source granule (swizzle)
    const int fl = flag[0];

    const unsigned short* Abf;
    const unsigned short* Bt;
    const float* bias;
    int z = 0, m0, n0, phase;
    if (MODE == 0) {
        // grid is (32,16,3); dispatch id -> XCD = id & 7 (round-robin)
        int bid = blockIdx.x + (blockIdx.y << 5) + (blockIdx.z << 9);
        int xcd = bid & 7, idx = bid >> 3;       // idx 0..191 within XCD
        z = idx >> 6;                            // 0..2
        int r = idx & 63;
        int mt = (xcd << 2) + (r & 3);           // XCD x owns m-tiles 4x..4x+3
        int nt = r >> 2;                         // 0..15
        m0 = mt * BM; n0 = nt * BN;
        phase = (nt * 13 + z * 5) & 31;          // same-B blocks K-aligned
        const void* Ain = (z == 0) ? A0 : (z == 1 ? A1 : A2);
        Abf = fl ? (const unsigned short*)Ain
                 : Aconv + (size_t)z * ((size_t)BS_ * D_);
        Bt = BtB + (size_t)z * D_ * D_;
        bias = biasB + z * 1024;
    } else {
        Abf = (const unsigned short*)A0;         // heads, always bf16
        Bt = BtB; bias = biasB;
        m0 = blockIdx.x * BM; n0 = blockIdx.y * BN;
        phase = (blockIdx.x * 7 + blockIdx.y * 13) & 31;
    }

    // stage K-slice kk into buffer bi (swizzled: slot s of row r holds
    // global granule s ^ ((r>>1)&3)) — pure DMA, A and B both bf16
    auto stage = [&](int kk, int bi) {
#pragma unroll
        for (int i = 0; i < CPW; ++i) {
            int c = w * CPW + i;
            int row = c * 16 + lr;
            const unsigned short* g;
            if (row < BM)
                g = Abf + (size_t)(m0 + row) * D_ + kk + lg * 8;
            else
                g = Bt + (size_t)(n0 + row - BM) * D_ + kk + lg * 8;
            gl2lds16(g, &buf[bi][c * 512]);
        }
    };

    f32x4 acc[MT][NT];
#pragma unroll
    for (int i = 0; i < MT; i++)
#pragma unroll
        for (int j = 0; j < NT; j++) acc[i][j] = (f32x4){0.f, 0.f, 0.f, 0.f};

    stage((phase & 31) * 32, 0);
    for (int it = 0; it < D_ / 32; ++it) {
        const int bi = it & 1;
        __syncthreads();                 // drains the prefetch of slice `it`
        if (it < D_ / 32 - 1) stage(((it + 1 + phase) & 31) * 32, bi ^ 1);

        const unsigned short* As = buf[bi];
        const unsigned short* Bs = buf[bi] + BM * 32;
        bf16x8 af[MT], bv[NT];
#pragma unroll
        for (int mt = 0; mt < MT; mt++) {
            int row = wm * (BM / 2) + mt * 16 + lm;
            af[mt] = *(const bf16x8*)&As[row * 32 + (q4 ^ ((row >> 1) & 3)) * 8];
        }
#pragma unroll
        for (int nt = 0; nt < NT; nt++) {
            int row = wn * (BN / 2) + nt * 16 + lm;
            bv[nt] = *(const bf16x8*)&Bs[row * 32 + (q4 ^ ((row >> 1) & 3)) * 8];
        }
#pragma unroll
        for (int mt = 0; mt < MT; mt++)
#pragma unroll
            for (int nt = 0; nt < NT; nt++)
                acc[mt][nt] = __builtin_amdgcn_mfma_f32_16x16x32_bf16(
                    af[mt], bv[nt], acc[mt][nt], 0, 0, 0);
    }

    // epilogue: C/D layout col=lane&15, row=(lane>>4)*4+reg
#pragma unroll
    for (int mt = 0; mt < MT; mt++)
#pragma unroll
        for (int nt = 0; nt < NT; nt++) {
            int N = n0 + wn * (BN / 2) + nt * 16 + lm;
            int Mb = m0 + wm * (BM / 2) + mt * 16 + q4 * 4;
            if (MODE == 0 && z == 2) {
                // V^T: 4 consecutive s per lane -> one b64 store
                int bb = Mb >> 10, sb = Mb & 1023, hh = N >> 6, e = N & 63;
                unsigned long long hv = 0;
#pragma unroll
                for (int r = 0; r < 4; r++)
                    hv |= (unsigned long long)f2bf(acc[mt][nt][r] + bias[N]) << (16 * r);
                unsigned short* d16 = (unsigned short*)dstB + (size_t)2 * BHSE_;
                *(unsigned long long*)&d16[(((size_t)(bb * H_ + hh) * E_ + e) << 10) + sb] = hv;
            } else {
#pragma unroll
                for (int r = 0; r < 4; r++) {
                    int M = Mb + r;
                    float v = acc[mt][nt][r] + bias[N];
                    if (MODE == 0) {
                        int bb = M >> 10, s = M & 1023, hh = N >> 6, e = N & 63;
                        unsigned short* d16 = (unsigned short*)dstB + (size_t)z * BHSE_;
                        d16[((size_t)(bb * H_ + hh) * S_ + s) * E_ + e] = f2bf(v);
                    } else {
                        size_t idx = (size_t)M * D_ + N;
                        if (fl) ((unsigned short*)dstB)[idx] = f2bf(v);
                        else    ((float*)dstB)[idx] = v;
                    }
                }
            }
        }
}

// ---------------------------------------------------------------------------
// Kernel 4 (R10): fused attention. CHANGED vs R9:
//  (1) Pw LDS scratch REMOVED — P's C->B redistribution now in-register:
//      v_cvt_pk_bf16_f32 packs p-pairs (8 ops replace ~90 VALU of manual
//      f2bf + u64 packing), then 16 ds_bpermute + 8 cndmask implement the
//      exact permutation the LDS round-trip did (dest lane (q4,lm) word t of
//      bp0 holds k=q4*8+2t(+1) <- source lane lm+(q4&1)*32(+16), reg
//      cl[2*(q4>>1)+h]). LDS 44 KB -> 32 KB => 5 blocks/CU (was 3), and the
//      stride-88 Pw bank conflicts (1.57M/dispatch) vanish.
//  (2) tile max over RAW scores (overestimate is softmax-safe); masked p
//      zeroed AFTER exp2 (double-masking semantics preserved); exp2 input is
//      a single fmaf(st, scale2, -mnew).
//  (3) defer-max (THR=8): wave-uniform skip of alpha/exp2/O-rescale when
//      __all(pmax - mrun <= 8).
// ---------------------------------------------------------------------------
__global__ __launch_bounds__(256, 5) void attn64(
        const unsigned short* Qp, const unsigned short* Kp, const unsigned short* VpT,
        const unsigned long long* packT, unsigned short* heads) {
    __shared__ unsigned short KT[2][4096];   // [buf][64 keys x 64 e], swizzled
    __shared__ unsigned short VT[2][4096];   // [buf][64 e x 64 keys], swizzled

    const int qt = blockIdx.x, h = blockIdx.y, b = blockIdx.z;
    const int t = threadIdx.x, w = t >> 6, lane = t & 63, lm = lane & 15, q4 = lane >> 4;
    const size_t bh = ((size_t)b * H_ + h) * S_ * E_;
    const unsigned short* Qb = Qp + bh;
    const unsigned short* Kb = Kp + bh;
    const unsigned short* Vb = VpT + bh;                // Vb[e*1024 + s]
    const int q0 = qt * 64 + w * 16;

    // per-lane invariant DMA source offsets (ushort units)
    const int l3 = lane >> 3, l7 = lane & 7;
    const int kLaneOff = l3 * 64 + (l7 ^ l3) * 8;       // within an 8-row K chunk
    const int vLaneOff = l3 * 1024 + (l7 ^ l3) * 8;     // within an 8-row V chunk

    // swizzled LDS fragment chunk indices (granule = 8 ushorts)
    const int sw = lm & 7;
    const int c0 = (q4 ^ sw) * 8, c1 = ((q4 ^ 4) ^ sw) * 8;

    // bpermute source byte-addresses for the P redistribution
    const int srcA4 = ((lane & 15) | ((lane & 16) << 1)) << 2;  // (lm+(q4&1)*32)*4
    const int srcB4 = srcA4 + 64;                               // +16 lanes
    const bool selHi = (lane & 32) != 0;                        // q4 >= 2

    // Q B-fragments, held for the whole sweep
    bf16x8 bq0 = *(const bf16x8*)&Qb[(size_t)(q0 + lm) * E_ + q4 * 8];
    bf16x8 bq1 = *(const bf16x8*)&Qb[(size_t)(q0 + lm) * E_ + 32 + q4 * 8];

    f32x4 oacc[4];
#pragma unroll
    for (int i = 0; i < 4; i++) oacc[i] = (f32x4){0.f, 0.f, 0.f, 0.f};
    float mrun = -3.0e38f, lrun = 0.f;
    const float scale2 = 0.03125f * 1.4426950408889634f;   // log2e / sqrt(D)

#define STAGE(ktile, bufi)                                                    \
    {                                                                         \
        int k0s = (ktile) * 64;                                               \
        _Pragma("unroll")                                                     \
        for (int i_ = 0; i_ < 4; ++i_) {                                      \
            int c_ = w * 4 + i_;                                              \
            if (c_ < 8) {                                                     \
                gl2lds16(Kb + (size_t)k0s * 64 + c_ * 512 + kLaneOff,         \
                         &KT[bufi][c_ * 512]);                                \
            } else {                                                          \
                int cc_ = c_ - 8;                                             \
                gl2lds16(Vb + (size_t)cc_ * 8192 + k0s + vLaneOff,            \
                         &VT[bufi][cc_ * 512]);                               \
            }                                                                 \
        }                                                                     \
    }

    STAGE(0, 0)

    for (int kt = 0; kt < S_ / 64; ++kt) {
        const int bufi = kt & 1;
        __syncthreads();                 // own-vmcnt drain + barrier: tile kt ready
        if (kt < 15) STAGE(kt + 1, bufi ^ 1)

        unsigned long long mk = packT[((size_t)b * 16 + kt) * 1024 + q0 + lm];

        // Sc^T from LDS K tile
        f32x4 st[4];
#pragma unroll
        for (int jt = 0; jt < 4; ++jt) {
            const unsigned short* kr = &KT[bufi][(jt * 16 + lm) * 64];
            bf16x8 ka0 = *(const bf16x8*)&kr[c0];
            bf16x8 ka1 = *(const bf16x8*)&kr[c1];
            f32x4 zz = (f32x4){0.f, 0.f, 0.f, 0.f};
            zz = __builtin_amdgcn_mfma_f32_16x16x32_bf16(ka0, bq0, zz, 0, 0, 0);
            zz = __builtin_amdgcn_mfma_f32_16x16x32_bf16(ka1, bq1, zz, 0, 0, 0);
            st[jt] = zz;
        }

        // raw tile max (masked entries included: harmless overestimate)
        float tmx = -3.0e38f;
#pragma unroll
        for (int jt = 0; jt < 4; ++jt)
#pragma unroll
            for (int r = 0; r < 4; r++) tmx = fmaxf(tmx, st[jt][r]);
        tmx = fmaxf(tmx, __shfl_xor(tmx, 16, 64));
        tmx = fmaxf(tmx, __shfl_xor(tmx, 32, 64));
        float pmax = tmx * scale2;                 // per-q (lm) scaled tile max

        // defer-max: only rescale when some row's max grew past THR=8
        if (!__all(pmax - mrun <= 8.f)) {
            float mnew = fmaxf(mrun, pmax);
            float alpha = EXP2(mrun - mnew);
            lrun *= alpha;
#pragma unroll
            for (int nt = 0; nt < 4; nt++) oacc[nt] = oacc[nt] * alpha;
            mrun = mnew;
        }
        const float mneg = -mrun;

        // per-lane mask nibbles: jt0/1 bits in mn (r, 16+r), jt2/3 in mh
        unsigned int mn = (unsigned int)(mk >> (q4 * 4));
        unsigned int mh = (unsigned int)(mk >> (q4 * 4 + 32));

        float ssum = 0.f;
        unsigned int cl[8];                        // packed bf16 pairs
#pragma unroll
        for (int jt = 0; jt < 4; ++jt) {
            unsigned int mm = (jt & 2) ? mh : mn;
            const int sh = (jt & 1) * 16;
            float p0 = EXP2(fmaf(st[jt][0], scale2, mneg));
            float p1 = EXP2(fmaf(st[jt][1], scale2, mneg));
            float p2 = EXP2(fmaf(st[jt][2], scale2, mneg));
            float p3 = EXP2(fmaf(st[jt][3], scale2, mneg));
            p0 = (mm & (1u << (sh + 0))) ? p0 : 0.f;
            p1 = (mm & (1u << (sh + 1))) ? p1 : 0.f;
            p2 = (mm & (1u << (sh + 2))) ? p2 : 0.f;
            p3 = (mm & (1u << (sh + 3))) ? p3 : 0.f;
            ssum += (p0 + p1) + (p2 + p3);
            cl[jt * 2]     = cvtpk(p0, p1);
            cl[jt * 2 + 1] = cvtpk(p2, p3);
        }
        ssum += __shfl_xor(ssum, 16, 64);
        ssum += __shfl_xor(ssum, 32, 64);
        lrun += ssum;

        // in-register C->B redistribution (replaces the Pw LDS round-trip):
        // bp0 word t holds k=q4*8+2t,+2t+1 for q=lm
        u32x4 w0, w1;
        {
            unsigned int aA0 = bperm(srcA4, cl[0]), aA2 = bperm(srcA4, cl[2]);
            unsigned int aA1 = bperm(srcA4, cl[1]), aA3 = bperm(srcA4, cl[3]);
            unsigned int aB0 = bperm(srcB4, cl[0]), aB2 = bperm(srcB4, cl[2]);
            unsigned int aB1 = bperm(srcB4, cl[1]), aB3 = bperm(srcB4, cl[3]);
            w0 = (u32x4){selHi ? aA2 : aA0, selHi ? aA3 : aA1,
                         selHi ? aB2 : aB0, selHi ? aB3 : aB1};
            unsigned int bA0 = bperm(srcA4, cl[4]), bA2 = bperm(srcA4, cl[6]);
            unsigned int bA1 = bperm(srcA4, cl[5]), bA3 = bperm(srcA4, cl[7]);
            unsigned int bB0 = bperm(srcB4, cl[4]), bB2 = bperm(srcB4, cl[6]);
            unsigned int bB1 = bperm(srcB4, cl[5]), bB3 = bperm(srcB4, cl[7]);
            w1 = (u32x4){selHi ? bA2 : bA0, selHi ? bA3 : bA1,
                         selHi ? bB2 : bB0, selHi ? bB3 : bB1};
        }
        bf16x8 bp0 = u4bf(w0);
        bf16x8 bp1 = u4bf(w1);

        // PV from LDS V tile
#pragma unroll
        for (int nt = 0; nt < 4; nt++) {
            const unsigned short* vr = &VT[bufi][(nt * 16 + lm) * 64];
            bf16x8 va0 = *(const bf16x8*)&vr[c0];
            bf16x8 va1 = *(const bf16x8*)&vr[c1];
            oacc[nt] = __builtin_amdgcn_mfma_f32_16x16x32_bf16(va0, bp0, oacc[nt], 0, 0, 0);
            oacc[nt] = __builtin_amdgcn_mfma_f32_16x16x32_bf16(va1, bp1, oacc[nt], 0, 0, 0);
        }
    }

    float inv = 1.0f / lrun;
#pragma unroll
    for (int nt = 0; nt < 4; nt++) {
        unsigned int lo = cvtpk(oacc[nt][0] * inv, oacc[nt][1] * inv);
        unsigned int hi = cvtpk(oacc[nt][2] * inv, oacc[nt][3] * inv);
        unsigned long long hv = (unsigned long long)lo | ((unsigned long long)hi << 32);
        *(unsigned long long*)&heads[(size_t)(b * S_ + q0 + lm) * D_ + h * E_ + nt * 16 + q4 * 4] = hv;
    }
}

// ---------------------------------------------------------------------------
extern "C" void kernel_launch(void* const* d_in, const int* in_sizes, int n_in,
                              void* d_out, int out_size, void* d_ws, size_t ws_size,
                              hipStream_t stream) {
    char* ws = (char*)d_ws;
    int* flag = (int*)ws;
    unsigned short* WT = (unsigned short*)(ws + 256);    // [4][1024][1024] bf16
    unsigned short* WqT = WT;
    unsigned short* WoT = WT + (size_t)3 * D_ * D_;
    float* biases = (float*)(WT + (size_t)4 * D_ * D_);  // [4][1024]
    float* bq = biases;
    float* bo = biases + 3 * 1024;
    unsigned short* Qp = (unsigned short*)(biases + 4 * 1024);  // [b][h][s][e]
    unsigned short* Kp = Qp + (size_t)BHSE_;                    // [b][h][s][e]
    unsigned short* Vp = Kp + (size_t)BHSE_;                    // [b][h][e][s]
    unsigned short* heads = Vp + (size_t)BHSE_;                 // [b*s][h*64+e]
    unsigned long long* packT = (unsigned long long*)(heads + (size_t)BHSE_);
    unsigned short* Aconv = (unsigned short*)(packT + (size_t)B_ * 16 * S_); // [3][4096][1024] bf16

    detect_dtype<<<1, 256, 0, stream>>>((const unsigned int*)d_in[0], flag);
    conv_w2<<<dim3(16, 16, 4), 256, 0, stream>>>(
        d_in[4], d_in[6], d_in[8], d_in[10],
        d_in[5], d_in[7], d_in[9], d_in[11], WT, biases, flag);
    maskpack<<<16384, 256, 0, stream>>>((const int*)d_in[3], packT);
    // one-shot fp32->bf16 A conversion (no-op when inputs already bf16)
    conv_a<<<6144, 256, 0, stream>>>(
        (const float*)d_in[0], (const float*)d_in[1], (const float*)d_in[2],
        Aconv, flag);
    // proj: 128x64 tiles -> 32 x 16 x 3 = 1536 blocks (6/CU), XCD m-stripes
    gemm_k<128, 64, 0, 4><<<dim3(32, 16, 3), 256, 0, stream>>>(
        d_in[0], d_in[1], d_in[2], Aconv, WqT, bq, Qp, flag);
    attn64<<<dim3(16, 16, 4), 256, 0, stream>>>(Qp, Kp, Vp, packT, heads);
    // final: 64x64 tiles -> 64 x 16 = 1024 blocks (4/CU), VGPR<=64 forced
    gemm_k<64, 64, 1, 8><<<dim3(64, 16, 1), 256, 0, stream>>>(
        heads, nullptr, nullptr, nullptr, WoT, bo, d_out, flag);
}

// Round 3
// 232.395 us; speedup vs baseline: 1.2671x; 1.0831x over previous
//
#include <hip/hip_runtime.h>

// Problem constants (B,S,D,H,HD) = (4,1024,1024,16,64)
#define B_ 4
#define S_ 1024
#define D_ 1024
#define H_ 16
#define E_ 64
#define BS_ (B_*S_)
#define BHSE_ (B_*H_*S_*E_)   // 4,194,304

typedef __attribute__((ext_vector_type(8))) short bf16x8;   // 8 bf16 in 4 VGPRs
typedef __attribute__((ext_vector_type(4))) float f32x4;
typedef __attribute__((ext_vector_type(4))) unsigned int u32x4;

__device__ __forceinline__ unsigned short f2bf(float f) {
    unsigned int x = __float_as_uint(f);
    x = (x + 0x7FFFu + ((x >> 16) & 1u)) >> 16;   // RNE
    return (unsigned short)x;
}
__device__ __forceinline__ float bf2f(unsigned short u) {
    return __uint_as_float(((unsigned int)u) << 16);
}
__device__ __forceinline__ float ldin(const void* p, size_t i, int isb) {
    return isb ? bf2f(((const unsigned short*)p)[i]) : ((const float*)p)[i];
}

// 2 f32 -> packed 2xbf16 in one VALU op (RNE) — no builtin on gfx950, asm it
__device__ __forceinline__ unsigned int cvtpk(float lo, float hi) {
    unsigned int r;
    asm("v_cvt_pk_bf16_f32 %0, %1, %2" : "=v"(r) : "v"(lo), "v"(hi));
    return r;
}
__device__ __forceinline__ unsigned int bperm(int srclane4, unsigned int v) {
    return (unsigned int)__builtin_amdgcn_ds_bpermute(srclane4, (int)v);
}
__device__ __forceinline__ bf16x8 u4bf(u32x4 w) {
    union { u32x4 u; bf16x8 h; } c; c.u = w; return c.h;
}

// 2^x : v_exp_f32 is natively base-2
#if __has_builtin(__builtin_amdgcn_exp2f)
#define EXP2(x) __builtin_amdgcn_exp2f(x)
#else
#define EXP2(x) __expf((x) * 0.6931471805599453f)
#endif

// async global->LDS, 16B per lane; LDS dest = wave-uniform base + lane*16
__device__ __forceinline__ void gl2lds16(const void* g, void* l) {
    __builtin_amdgcn_global_load_lds(
        (const __attribute__((address_space(1))) void*)g,
        (__attribute__((address_space(3))) void*)l, 16, 0, 0);
}

// ---------------------------------------------------------------------------
// R11: per-block dtype self-detect (replaces the serializing 1-block
// detect_dtype kernel). One 64-word coalesced read of q + one wave ballot;
// all waves of the block compute the identical answer independently.
// bf16 data: low 16 bits are a bf16 value -> exp field in [100,145] (or 0)
// for ~all N(0,1) samples; fp32 data: low 16 bits are mantissa noise (~18%
// hit rate). Threshold 48/64 == old 240/256.
// Must be called with all lanes active (kernel entry).
// ---------------------------------------------------------------------------
__device__ __forceinline__ int detect_isb(const unsigned int* q) {
    unsigned int wv = q[threadIdx.x & 63];
    unsigned int lo = wv & 0xFFFFu;
    unsigned int e = (lo >> 7) & 0xFFu;
    int ok = (lo == 0u) || (e >= 100u && e <= 145u);
    return __popcll(__ballot(ok)) >= 48;
}

// ---------------------------------------------------------------------------
// Kernel 1 (R11): merged preprocessing — one dispatch replaces
// detect_dtype + conv_w2 + maskpack + conv_a (4 serialized launches).
// blocks [0,1024):          weight permutes (LDS-transposed 64x64 tiles)
//   z=0..2: W{q,k,v}[h][d][e] -> WT[z][(h*64+e)][d]; z=3: Wo[d][o]->WT[3][o][d]
// blocks [1024,5120):       mask bitpack, 4 ballots/wave:
//   packT[b][kt][s] bit k = mask[b][s][kt*64+k]
// blocks [5120,11264):      q,k,v fp32->bf16 one-shot convert (skip if bf16)
// ---------------------------------------------------------------------------
__global__ __launch_bounds__(256) void preproc(
        const void* q_, const void* k_, const void* v_, const int* mask,
        const void* Wq, const void* Wk, const void* Wv, const void* Wo,
        const void* bq_, const void* bk_, const void* bv_, const void* bo_,
        unsigned short* WT, float* biases, unsigned long long* packT,
        unsigned short* Aconv) {
    __shared__ unsigned short Tt[64][72];
    const int isb = detect_isb((const unsigned int*)q_);
    const int blk = blockIdx.x, t = threadIdx.x;

    if (blk < 1024) {
        // ---- weight permute ----
        const int c0 = blk & 15, r0 = ((blk >> 4) & 15) * 64, z = blk >> 8;
        const void* src = (z == 0) ? Wq : (z == 1) ? Wk : (z == 2) ? Wv : Wo;
        {
            int dl = t >> 2, qc = t & 3;
            size_t base;
            if (z < 3) base = (size_t)c0 * 65536 + (size_t)(r0 + dl) * 64 + qc * 16;
            else       base = (size_t)(r0 + dl) * 1024 + (size_t)c0 * 64 + qc * 16;
            if (isb) {
                const unsigned short* s = (const unsigned short*)src + base;
                bf16x8 a0 = *(const bf16x8*)s, a1 = *(const bf16x8*)(s + 8);
#pragma unroll
                for (int j = 0; j < 8; j++) {
                    Tt[qc * 16 + j][dl] = (unsigned short)a0[j];
                    Tt[qc * 16 + 8 + j][dl] = (unsigned short)a1[j];
                }
            } else {
                const float* s = (const float*)src + base;
#pragma unroll
                for (int j = 0; j < 16; j++) Tt[qc * 16 + j][dl] = f2bf(s[j]);
            }
        }
        __syncthreads();
        {
            int el = t >> 2, qc = t & 3;
            size_t dst = (size_t)z * D_ * D_ + (size_t)(c0 * 64 + el) * D_ + r0 + qc * 16;
            *(bf16x8*)&WT[dst]     = *(const bf16x8*)&Tt[el][qc * 16];
            *(bf16x8*)&WT[dst + 8] = *(const bf16x8*)&Tt[el][qc * 16 + 8];
        }
        if (z == 3 && ((blk >> 4) & 15) == 0 && c0 < 4) {
            const void* bs = (c0 == 0) ? bq_ : (c0 == 1) ? bk_
                           : (c0 == 2) ? bv_ : bo_;
#pragma unroll
            for (int j = 0; j < 4; j++) {
                int i = t * 4 + j;
                biases[c0 * 1024 + i] = ldin(bs, i, isb);
            }
        }
    } else if (blk < 5120) {
        // ---- mask bitpack: unit = (b, kt, 4 s-rows) per wave ----
        int unit = (blk - 1024) * 4 + (t >> 6);
        int lane = t & 63;
        int b = unit >> 12, rem = unit & 4095, s0 = (rem >> 4) * 4, kt = rem & 15;
        const int* mb = mask + ((size_t)b * 1024 + s0) * 1024 + kt * 64 + lane;
        unsigned long long bits[4];
#pragma unroll
        for (int j = 0; j < 4; j++) bits[j] = __ballot(mb[j * 1024] != 0);
        if (lane < 4) {
            unsigned long long bb = (lane == 0) ? bits[0] : (lane == 1) ? bits[1]
                                  : (lane == 2) ? bits[2] : bits[3];
            packT[((size_t)b * 16 + kt) * 1024 + s0 + lane] = bb;
        }
    } else {
        // ---- q,k,v fp32 -> bf16 ----
        if (isb) return;
        int blk2 = blk - 5120;
        const int z = blk2 >> 11;
        const float* s = (z == 0) ? (const float*)q_ : (z == 1) ? (const float*)k_
                                                                : (const float*)v_;
        const size_t i = ((size_t)(blk2 & 2047) * 256 + t) * 8;
        f32x4 a0 = *(const f32x4*)(s + i);
        f32x4 a1 = *(const f32x4*)(s + i + 4);
        bf16x8 o;
#pragma unroll
        for (int j = 0; j < 4; j++) {
            o[j]     = (short)f2bf(a0[j]);
            o[4 + j] = (short)f2bf(a1[j]);
        }
        *(bf16x8*)&Aconv[(size_t)z * ((size_t)BS_ * D_) + i] = o;
    }
}

// ---------------------------------------------------------------------------
// Kernel 3 (R11): bf16 MFMA GEMM. Internals unchanged (DMA dbuf, one
// barrier/iter, XOR-4 swizzle). CHANGED: MODE 0 tile 128x64 -> 128x128 (the
// verified m97/m103 config: 16 MFMA per 8 ds_read_b128 per wave per K-step,
// 2x the MFMA:LDS ratio of 128x64). Grid (32,8,3)=768 blocks, 3/CU.
// XCD remap: xcd owns m-stripe [4x,4x+4) for all (n,z); z phases are
// dispatch-sequential -> 1MB A-slice + 2MB B per z resident in XCD L2.
// Dtype flag is now per-block self-detected from q (no flag kernel).
// MODE 0: 3 projections (z: Q,K -> [b][h][s][e]; V -> [b][h][e][s]).
// MODE 1: final GEMM (A=heads bf16), writes d_out per detected dtype.
// ---------------------------------------------------------------------------
template<int BM, int BN, int MODE, int MINW>
__global__ __launch_bounds__(256, MINW) void gemm_k(
        const void* A0, const void* A1, const void* A2, const unsigned short* Aconv,
        const unsigned short* BtB, const float* biasB, void* dstB,
        const unsigned int* qdet) {
    constexpr int TOT16 = (BM + BN) * 32;       // ushorts per buffer
    constexpr int CALLS = TOT16 / 512;          // 1KB chunks (16 rows x 32 cols)
    constexpr int CPW = CALLS / 4;
    constexpr int MT = BM / 32;                 // wave-tile (BM/2)x(BN/2)
    constexpr int NT = BN / 32;
    __shared__ unsigned short buf[2][TOT16];

    const int fl = detect_isb(qdet);
    const int t = threadIdx.x, lane = t & 63, w = t >> 6;
    const int lm = lane & 15, q4 = lane >> 4;
    const int wm = w >> 1, wn = w & 1;
    const int lr = lane >> 2;                    // row-in-chunk 0..15
    const int ls = lane & 3;                     // LDS slot 0..3
    const int lg = ls ^ ((lr >> 1) & 3);         // source granule (swizzle)

    const unsigned short* Abf;
    const unsigned short* Bt;
    const float* bias;
    int z = 0, m0, n0, phase;
    if (MODE == 0) {
        // grid (32,8,3); dispatch id -> XCD = id & 7 (round-robin)
        int bid = blockIdx.x + gridDim.x * (blockIdx.y + gridDim.y * blockIdx.z);
        int xcd = bid & 7, idx = bid >> 3;       // idx 0..95 within XCD
        z = idx >> 5;                            // 0..2 (sequential per XCD)
        int r = idx & 31;
        int mt = (xcd << 2) + (r & 3);           // XCD x owns m-tiles 4x..4x+3
        int nt = r >> 2;                         // 0..7
        m0 = mt * BM; n0 = nt * BN;
        phase = (nt * 13 + z * 5) & 31;          // same-B blocks K-aligned
        const void* Ain = (z == 0) ? A0 : (z == 1 ? A1 : A2);
        Abf = fl ? (const unsigned short*)Ain
                 : Aconv + (size_t)z * ((size_t)BS_ * D_);
        Bt = BtB + (size_t)z * D_ * D_;
        bias = biasB + z * 1024;
    } else {
        Abf = (const unsigned short*)A0;         // heads, always bf16
        Bt = BtB; bias = biasB;
        m0 = blockIdx.x * BM; n0 = blockIdx.y * BN;
        phase = (blockIdx.x * 7 + blockIdx.y * 13) & 31;
    }

    // stage K-slice kk into buffer bi (swizzled: slot s of row r holds
    // global granule s ^ ((r>>1)&3)) — pure DMA, A and B both bf16
    auto stage = [&](int kk, int bi) {
#pragma unroll
        for (int i = 0; i < CPW; ++i) {
            int c = w * CPW + i;
            int row = c * 16 + lr;
            const unsigned short* g;
            if (row < BM)
                g = Abf + (size_t)(m0 + row) * D_ + kk + lg * 8;
            else
                g = Bt + (size_t)(n0 + row - BM) * D_ + kk + lg * 8;
            gl2lds16(g, &buf[bi][c * 512]);
        }
    };

    f32x4 acc[MT][NT];
#pragma unroll
    for (int i = 0; i < MT; i++)
#pragma unroll
        for (int j = 0; j < NT; j++) acc[i][j] = (f32x4){0.f, 0.f, 0.f, 0.f};

    stage((phase & 31) * 32, 0);
    for (int it = 0; it < D_ / 32; ++it) {
        const int bi = it & 1;
        __syncthreads();                 // drains the prefetch of slice `it`
        if (it < D_ / 32 - 1) stage(((it + 1 + phase) & 31) * 32, bi ^ 1);

        const unsigned short* As = buf[bi];
        const unsigned short* Bs = buf[bi] + BM * 32;
        bf16x8 af[MT], bv[NT];
#pragma unroll
        for (int mt = 0; mt < MT; mt++) {
            int row = wm * (BM / 2) + mt * 16 + lm;
            af[mt] = *(const bf16x8*)&As[row * 32 + (q4 ^ ((row >> 1) & 3)) * 8];
        }
#pragma unroll
        for (int nt = 0; nt < NT; nt++) {
            int row = wn * (BN / 2) + nt * 16 + lm;
            bv[nt] = *(const bf16x8*)&Bs[row * 32 + (q4 ^ ((row >> 1) & 3)) * 8];
        }
#pragma unroll
        for (int mt = 0; mt < MT; mt++)
#pragma unroll
            for (int nt = 0; nt < NT; nt++)
                acc[mt][nt] = __builtin_amdgcn_mfma_f32_16x16x32_bf16(
                    af[mt], bv[nt], acc[mt][nt], 0, 0, 0);
    }

    // epilogue: C/D layout col=lane&15, row=(lane>>4)*4+reg
#pragma unroll
    for (int mt = 0; mt < MT; mt++)
#pragma unroll
        for (int nt = 0; nt < NT; nt++) {
            int N = n0 + wn * (BN / 2) + nt * 16 + lm;
            int Mb = m0 + wm * (BM / 2) + mt * 16 + q4 * 4;
            if (MODE == 0 && z == 2) {
                // V^T: 4 consecutive s per lane -> one b64 store
                int bb = Mb >> 10, sb = Mb & 1023, hh = N >> 6, e = N & 63;
                unsigned long long hv = 0;
#pragma unroll
                for (int r = 0; r < 4; r++)
                    hv |= (unsigned long long)f2bf(acc[mt][nt][r] + bias[N]) << (16 * r);
                unsigned short* d16 = (unsigned short*)dstB + (size_t)2 * BHSE_;
                *(unsigned long long*)&d16[(((size_t)(bb * H_ + hh) * E_ + e) << 10) + sb] = hv;
            } else {
#pragma unroll
                for (int r = 0; r < 4; r++) {
                    int M = Mb + r;
                    float v = acc[mt][nt][r] + bias[N];
                    if (MODE == 0) {
                        int bb = M >> 10, s = M & 1023, hh = N >> 6, e = N & 63;
                        unsigned short* d16 = (unsigned short*)dstB + (size_t)z * BHSE_;
                        d16[((size_t)(bb * H_ + hh) * S_ + s) * E_ + e] = f2bf(v);
                    } else {
                        size_t idx = (size_t)M * D_ + N;
                        if (fl) ((unsigned short*)dstB)[idx] = f2bf(v);
                        else    ((float*)dstB)[idx] = v;
                    }
                }
            }
        }
}

// ---------------------------------------------------------------------------
// Kernel 4: fused attention — unchanged from R10 (in-register P
// redistribution via cvt_pk+bpermute, raw-score max, defer-max THR=8,
// 32 KB LDS -> 5 blocks/CU).
// ---------------------------------------------------------------------------
__global__ __launch_bounds__(256, 5) void attn64(
        const unsigned short* Qp, const unsigned short* Kp, const unsigned short* VpT,
        const unsigned long long* packT, unsigned short* heads) {
    __shared__ unsigned short KT[2][4096];   // [buf][64 keys x 64 e], swizzled
    __shared__ unsigned short VT[2][4096];   // [buf][64 e x 64 keys], swizzled

    const int qt = blockIdx.x, h = blockIdx.y, b = blockIdx.z;
    const int t = threadIdx.x, w = t >> 6, lane = t & 63, lm = lane & 15, q4 = lane >> 4;
    const size_t bh = ((size_t)b * H_ + h) * S_ * E_;
    const unsigned short* Qb = Qp + bh;
    const unsigned short* Kb = Kp + bh;
    const unsigned short* Vb = VpT + bh;                // Vb[e*1024 + s]
    const int q0 = qt * 64 + w * 16;

    // per-lane invariant DMA source offsets (ushort units)
    const int l3 = lane >> 3, l7 = lane & 7;
    const int kLaneOff = l3 * 64 + (l7 ^ l3) * 8;       // within an 8-row K chunk
    const int vLaneOff = l3 * 1024 + (l7 ^ l3) * 8;     // within an 8-row V chunk

    // swizzled LDS fragment chunk indices (granule = 8 ushorts)
    const int sw = lm & 7;
    const int c0 = (q4 ^ sw) * 8, c1 = ((q4 ^ 4) ^ sw) * 8;

    // bpermute source byte-addresses for the P redistribution
    const int srcA4 = ((lane & 15) | ((lane & 16) << 1)) << 2;  // (lm+(q4&1)*32)*4
    const int srcB4 = srcA4 + 64;                               // +16 lanes
    const bool selHi = (lane & 32) != 0;                        // q4 >= 2

    // Q B-fragments, held for the whole sweep
    bf16x8 bq0 = *(const bf16x8*)&Qb[(size_t)(q0 + lm) * E_ + q4 * 8];
    bf16x8 bq1 = *(const bf16x8*)&Qb[(size_t)(q0 + lm) * E_ + 32 + q4 * 8];

    f32x4 oacc[4];
#pragma unroll
    for (int i = 0; i < 4; i++) oacc[i] = (f32x4){0.f, 0.f, 0.f, 0.f};
    float mrun = -3.0e38f, lrun = 0.f;
    const float scale2 = 0.03125f * 1.4426950408889634f;   // log2e / sqrt(D)

#define STAGE(ktile, bufi)                                                    \
    {                                                                         \
        int k0s = (ktile) * 64;                                               \
        _Pragma("unroll")                                                     \
        for (int i_ = 0; i_ < 4; ++i_) {                                      \
            int c_ = w * 4 + i_;                                              \
            if (c_ < 8) {                                                     \
                gl2lds16(Kb + (size_t)k0s * 64 + c_ * 512 + kLaneOff,         \
                         &KT[bufi][c_ * 512]);                                \
            } else {                                                          \
                int cc_ = c_ - 8;                                             \
                gl2lds16(Vb + (size_t)cc_ * 8192 + k0s + vLaneOff,            \
                         &VT[bufi][cc_ * 512]);                               \
            }                                                                 \
        }                                                                     \
    }

    STAGE(0, 0)

    for (int kt = 0; kt < S_ / 64; ++kt) {
        const int bufi = kt & 1;
        __syncthreads();                 // own-vmcnt drain + barrier: tile kt ready
        if (kt < 15) STAGE(kt + 1, bufi ^ 1)

        unsigned long long mk = packT[((size_t)b * 16 + kt) * 1024 + q0 + lm];

        // Sc^T from LDS K tile
        f32x4 st[4];
#pragma unroll
        for (int jt = 0; jt < 4; ++jt) {
            const unsigned short* kr = &KT[bufi][(jt * 16 + lm) * 64];
            bf16x8 ka0 = *(const bf16x8*)&kr[c0];
            bf16x8 ka1 = *(const bf16x8*)&kr[c1];
            f32x4 zz = (f32x4){0.f, 0.f, 0.f, 0.f};
            zz = __builtin_amdgcn_mfma_f32_16x16x32_bf16(ka0, bq0, zz, 0, 0, 0);
            zz = __builtin_amdgcn_mfma_f32_16x16x32_bf16(ka1, bq1, zz, 0, 0, 0);
            st[jt] = zz;
        }

        // raw tile max (masked entries included: harmless overestimate)
        float tmx = -3.0e38f;
#pragma unroll
        for (int jt = 0; jt < 4; ++jt)
#pragma unroll
            for (int r = 0; r < 4; r++) tmx = fmaxf(tmx, st[jt][r]);
        tmx = fmaxf(tmx, __shfl_xor(tmx, 16, 64));
        tmx = fmaxf(tmx, __shfl_xor(tmx, 32, 64));
        float pmax = tmx * scale2;                 // per-q (lm) scaled tile max

        // defer-max: only rescale when some row's max grew past THR=8
        if (!__all(pmax - mrun <= 8.f)) {
            float mnew = fmaxf(mrun, pmax);
            float alpha = EXP2(mrun - mnew);
            lrun *= alpha;
#pragma unroll
            for (int nt = 0; nt < 4; nt++) oacc[nt] = oacc[nt] * alpha;
            mrun = mnew;
        }
        const float mneg = -mrun;

        // per-lane mask nibbles: jt0/1 bits in mn (r, 16+r), jt2/3 in mh
        unsigned int mn = (unsigned int)(mk >> (q4 * 4));
        unsigned int mh = (unsigned int)(mk >> (q4 * 4 + 32));

        float ssum = 0.f;
        unsigned int cl[8];                        // packed bf16 pairs
#pragma unroll
        for (int jt = 0; jt < 4; ++jt) {
            unsigned int mm = (jt & 2) ? mh : mn;
            const int sh = (jt & 1) * 16;
            float p0 = EXP2(fmaf(st[jt][0], scale2, mneg));
            float p1 = EXP2(fmaf(st[jt][1], scale2, mneg));
            float p2 = EXP2(fmaf(st[jt][2], scale2, mneg));
            float p3 = EXP2(fmaf(st[jt][3], scale2, mneg));
            p0 = (mm & (1u << (sh + 0))) ? p0 : 0.f;
            p1 = (mm & (1u << (sh + 1))) ? p1 : 0.f;
            p2 = (mm & (1u << (sh + 2))) ? p2 : 0.f;
            p3 = (mm & (1u << (sh + 3))) ? p3 : 0.f;
            ssum += (p0 + p1) + (p2 + p3);
            cl[jt * 2]     = cvtpk(p0, p1);
            cl[jt * 2 + 1] = cvtpk(p2, p3);
        }
        ssum += __shfl_xor(ssum, 16, 64);
        ssum += __shfl_xor(ssum, 32, 64);
        lrun += ssum;

        // in-register C->B redistribution (replaces the Pw LDS round-trip):
        // bp0 word t holds k=q4*8+2t,+2t+1 for q=lm
        u32x4 w0, w1;
        {
            unsigned int aA0 = bperm(srcA4, cl[0]), aA2 = bperm(srcA4, cl[2]);
            unsigned int aA1 = bperm(srcA4, cl[1]), aA3 = bperm(srcA4, cl[3]);
            unsigned int aB0 = bperm(srcB4, cl[0]), aB2 = bperm(srcB4, cl[2]);
            unsigned int aB1 = bperm(srcB4, cl[1]), aB3 = bperm(srcB4, cl[3]);
            w0 = (u32x4){selHi ? aA2 : aA0, selHi ? aA3 : aA1,
                         selHi ? aB2 : aB0, selHi ? aB3 : aB1};
            unsigned int bA0 = bperm(srcA4, cl[4]), bA2 = bperm(srcA4, cl[6]);
            unsigned int bA1 = bperm(srcA4, cl[5]), bA3 = bperm(srcA4, cl[7]);
            unsigned int bB0 = bperm(srcB4, cl[4]), bB2 = bperm(srcB4, cl[6]);
            unsigned int bB1 = bperm(srcB4, cl[5]), bB3 = bperm(srcB4, cl[7]);
            w1 = (u32x4){selHi ? bA2 : bA0, selHi ? bA3 : bA1,
                         selHi ? bB2 : bB0, selHi ? bB3 : bB1};
        }
        bf16x8 bp0 = u4bf(w0);
        bf16x8 bp1 = u4bf(w1);

        // PV from LDS V tile
#pragma unroll
        for (int nt = 0; nt < 4; nt++) {
            const unsigned short* vr = &VT[bufi][(nt * 16 + lm) * 64];
            bf16x8 va0 = *(const bf16x8*)&vr[c0];
            bf16x8 va1 = *(const bf16x8*)&vr[c1];
            oacc[nt] = __builtin_amdgcn_mfma_f32_16x16x32_bf16(va0, bp0, oacc[nt], 0, 0, 0);
            oacc[nt] = __builtin_amdgcn_mfma_f32_16x16x32_bf16(va1, bp1, oacc[nt], 0, 0, 0);
        }
    }

    float inv = 1.0f / lrun;
#pragma unroll
    for (int nt = 0; nt < 4; nt++) {
        unsigned int lo = cvtpk(oacc[nt][0] * inv, oacc[nt][1] * inv);
        unsigned int hi = cvtpk(oacc[nt][2] * inv, oacc[nt][3] * inv);
        unsigned long long hv = (unsigned long long)lo | ((unsigned long long)hi << 32);
        *(unsigned long long*)&heads[(size_t)(b * S_ + q0 + lm) * D_ + h * E_ + nt * 16 + q4 * 4] = hv;
    }
}

// ---------------------------------------------------------------------------
extern "C" void kernel_launch(void* const* d_in, const int* in_sizes, int n_in,
                              void* d_out, int out_size, void* d_ws, size_t ws_size,
                              hipStream_t stream) {
    char* ws = (char*)d_ws;
    unsigned short* WT = (unsigned short*)(ws + 256);    // [4][1024][1024] bf16
    unsigned short* WqT = WT;
    unsigned short* WoT = WT + (size_t)3 * D_ * D_;
    float* biases = (float*)(WT + (size_t)4 * D_ * D_);  // [4][1024]
    float* bq = biases;
    float* bo = biases + 3 * 1024;
    unsigned short* Qp = (unsigned short*)(biases + 4 * 1024);  // [b][h][s][e]
    unsigned short* Kp = Qp + (size_t)BHSE_;                    // [b][h][s][e]
    unsigned short* Vp = Kp + (size_t)BHSE_;                    // [b][h][e][s]
    unsigned short* heads = Vp + (size_t)BHSE_;                 // [b*s][h*64+e]
    unsigned long long* packT = (unsigned long long*)(heads + (size_t)BHSE_);
    unsigned short* Aconv = (unsigned short*)(packT + (size_t)B_ * 16 * S_); // [3][4096][1024] bf16

    // merged preprocessing: weights + bias, mask bitpack, A fp32->bf16
    preproc<<<11264, 256, 0, stream>>>(
        d_in[0], d_in[1], d_in[2], (const int*)d_in[3],
        d_in[4], d_in[6], d_in[8], d_in[10],
        d_in[5], d_in[7], d_in[9], d_in[11],
        WT, biases, packT, Aconv);
    // proj: 128x128 tiles -> 32 x 8 x 3 = 768 blocks (3/CU), XCD m-stripes
    gemm_k<128, 128, 0, 3><<<dim3(32, 8, 3), 256, 0, stream>>>(
        d_in[0], d_in[1], d_in[2], Aconv, WqT, bq, Qp,
        (const unsigned int*)d_in[0]);
    attn64<<<dim3(16, 16, 4), 256, 0, stream>>>(Qp, Kp, Vp, packT, heads);
    // final: 64x64 tiles -> 64 x 16 = 1024 blocks (4/CU), VGPR<=64 forced
    gemm_k<64, 64, 1, 8><<<dim3(64, 16, 1), 256, 0, stream>>>(
        heads, nullptr, nullptr, nullptr, WoT, bo, d_out,
        (const unsigned int*)d_in[0]);
}

// Round 4
// 225.818 us; speedup vs baseline: 1.3040x; 1.0291x over previous
//
#include <hip/hip_runtime.h>

// Problem constants (B,S,D,H,HD) = (4,1024,1024,16,64)
#define B_ 4
#define S_ 1024
#define D_ 1024
#define H_ 16
#define E_ 64
#define BS_ (B_*S_)
#define BHSE_ (B_*H_*S_*E_)   // 4,194,304

typedef __attribute__((ext_vector_type(8))) short bf16x8;   // 8 bf16 in 4 VGPRs
typedef __attribute__((ext_vector_type(4))) float f32x4;
typedef __attribute__((ext_vector_type(4))) unsigned int u32x4;

__device__ __forceinline__ unsigned short f2bf(float f) {
    unsigned int x = __float_as_uint(f);
    x = (x + 0x7FFFu + ((x >> 16) & 1u)) >> 16;   // RNE
    return (unsigned short)x;
}
__device__ __forceinline__ float bf2f(unsigned short u) {
    return __uint_as_float(((unsigned int)u) << 16);
}
__device__ __forceinline__ float ldin(const void* p, size_t i, int isb) {
    return isb ? bf2f(((const unsigned short*)p)[i]) : ((const float*)p)[i];
}

// 2 f32 -> packed 2xbf16 in one VALU op (RNE) — no builtin on gfx950, asm it
__device__ __forceinline__ unsigned int cvtpk(float lo, float hi) {
    unsigned int r;
    asm("v_cvt_pk_bf16_f32 %0, %1, %2" : "=v"(r) : "v"(lo), "v"(hi));
    return r;
}
__device__ __forceinline__ unsigned int bperm(int srclane4, unsigned int v) {
    return (unsigned int)__builtin_amdgcn_ds_bpermute(srclane4, (int)v);
}
__device__ __forceinline__ bf16x8 u4bf(u32x4 w) {
    union { u32x4 u; bf16x8 h; } c; c.u = w; return c.h;
}

// 2^x : v_exp_f32 is natively base-2
#if __has_builtin(__builtin_amdgcn_exp2f)
#define EXP2(x) __builtin_amdgcn_exp2f(x)
#else
#define EXP2(x) __expf((x) * 0.6931471805599453f)
#endif

// async global->LDS, 16B per lane; LDS dest = wave-uniform base + lane*16
__device__ __forceinline__ void gl2lds16(const void* g, void* l) {
    __builtin_amdgcn_global_load_lds(
        (const __attribute__((address_space(1))) void*)g,
        (__attribute__((address_space(3))) void*)l, 16, 0, 0);
}

// ---------------------------------------------------------------------------
// Per-block dtype self-detect. One 64-word coalesced read of q + one wave
// ballot; all waves compute the identical answer. Threshold 48/64.
// ---------------------------------------------------------------------------
__device__ __forceinline__ int detect_isb(const unsigned int* q) {
    unsigned int wv = q[threadIdx.x & 63];
    unsigned int lo = wv & 0xFFFFu;
    unsigned int e = (lo >> 7) & 0xFFu;
    int ok = (lo == 0u) || (e >= 100u && e <= 145u);
    return __popcll(__ballot(ok)) >= 48;
}

// ---------------------------------------------------------------------------
// Kernel 1: merged preprocessing — weights permute, mask bitpack, A convert.
// blocks [0,1024):     W{q,k,v}[h][d][e] -> WT[z][(h*64+e)][d]; Wo[d][o]->WT[3][o][d]
// blocks [1024,5120):  packT[b][kt][s] bit k = mask[b][s][kt*64+k]
// blocks [5120,11264): q,k,v fp32->bf16 one-shot convert (skip if bf16)
// ---------------------------------------------------------------------------
__global__ __launch_bounds__(256) void preproc(
        const void* q_, const void* k_, const void* v_, const int* mask,
        const void* Wq, const void* Wk, const void* Wv, const void* Wo,
        const void* bq_, const void* bk_, const void* bv_, const void* bo_,
        unsigned short* WT, float* biases, unsigned long long* packT,
        unsigned short* Aconv) {
    __shared__ unsigned short Tt[64][72];
    const int isb = detect_isb((const unsigned int*)q_);
    const int blk = blockIdx.x, t = threadIdx.x;

    if (blk < 1024) {
        // ---- weight permute ----
        const int c0 = blk & 15, r0 = ((blk >> 4) & 15) * 64, z = blk >> 8;
        const void* src = (z == 0) ? Wq : (z == 1) ? Wk : (z == 2) ? Wv : Wo;
        {
            int dl = t >> 2, qc = t & 3;
            size_t base;
            if (z < 3) base = (size_t)c0 * 65536 + (size_t)(r0 + dl) * 64 + qc * 16;
            else       base = (size_t)(r0 + dl) * 1024 + (size_t)c0 * 64 + qc * 16;
            if (isb) {
                const unsigned short* s = (const unsigned short*)src + base;
                bf16x8 a0 = *(const bf16x8*)s, a1 = *(const bf16x8*)(s + 8);
#pragma unroll
                for (int j = 0; j < 8; j++) {
                    Tt[qc * 16 + j][dl] = (unsigned short)a0[j];
                    Tt[qc * 16 + 8 + j][dl] = (unsigned short)a1[j];
                }
            } else {
                const float* s = (const float*)src + base;
#pragma unroll
                for (int j = 0; j < 16; j++) Tt[qc * 16 + j][dl] = f2bf(s[j]);
            }
        }
        __syncthreads();
        {
            int el = t >> 2, qc = t & 3;
            size_t dst = (size_t)z * D_ * D_ + (size_t)(c0 * 64 + el) * D_ + r0 + qc * 16;
            *(bf16x8*)&WT[dst]     = *(const bf16x8*)&Tt[el][qc * 16];
            *(bf16x8*)&WT[dst + 8] = *(const bf16x8*)&Tt[el][qc * 16 + 8];
        }
        if (z == 3 && ((blk >> 4) & 15) == 0 && c0 < 4) {
            const void* bs = (c0 == 0) ? bq_ : (c0 == 1) ? bk_
                           : (c0 == 2) ? bv_ : bo_;
#pragma unroll
            for (int j = 0; j < 4; j++) {
                int i = t * 4 + j;
                biases[c0 * 1024 + i] = ldin(bs, i, isb);
            }
        }
    } else if (blk < 5120) {
        // ---- mask bitpack: unit = (b, kt, 4 s-rows) per wave ----
        int unit = (blk - 1024) * 4 + (t >> 6);
        int lane = t & 63;
        int b = unit >> 12, rem = unit & 4095, s0 = (rem >> 4) * 4, kt = rem & 15;
        const int* mb = mask + ((size_t)b * 1024 + s0) * 1024 + kt * 64 + lane;
        unsigned long long bits[4];
#pragma unroll
        for (int j = 0; j < 4; j++) bits[j] = __ballot(mb[j * 1024] != 0);
        if (lane < 4) {
            unsigned long long bb = (lane == 0) ? bits[0] : (lane == 1) ? bits[1]
                                  : (lane == 2) ? bits[2] : bits[3];
            packT[((size_t)b * 16 + kt) * 1024 + s0 + lane] = bb;
        }
    } else {
        // ---- q,k,v fp32 -> bf16 ----
        if (isb) return;
        int blk2 = blk - 5120;
        const int z = blk2 >> 11;
        const float* s = (z == 0) ? (const float*)q_ : (z == 1) ? (const float*)k_
                                                                : (const float*)v_;
        const size_t i = ((size_t)(blk2 & 2047) * 256 + t) * 8;
        f32x4 a0 = *(const f32x4*)(s + i);
        f32x4 a1 = *(const f32x4*)(s + i + 4);
        bf16x8 o;
#pragma unroll
        for (int j = 0; j < 4; j++) {
            o[j]     = (short)f2bf(a0[j]);
            o[4 + j] = (short)f2bf(a1[j]);
        }
        *(bf16x8*)&Aconv[(size_t)z * ((size_t)BS_ * D_) + i] = o;
    }
}

// ---------------------------------------------------------------------------
// Kernel 3 (R12): bf16 MFMA GEMM (DMA dbuf, one barrier/iter, XOR-4 swizzle).
// MODE 0: proj, 128x128 tiles, grid (32,8,3), XCD m-stripes (unchanged).
// MODE 1 (CHANGED): final GEMM now 128x64 tiles, grid (32,16) = 512 blocks,
// with the same XCD m-stripe remap (xcd owns m-tiles [4x,4x+4) for all 16
// n-tiles -> 1MB A-slice L2-resident per XCD; MFMA:ds ratio 2.67 vs 1.33
// of the old 64x64).
// ---------------------------------------------------------------------------
template<int BM, int BN, int MODE, int MINW>
__global__ __launch_bounds__(256, MINW) void gemm_k(
        const void* A0, const void* A1, const void* A2, const unsigned short* Aconv,
        const unsigned short* BtB, const float* biasB, void* dstB,
        const unsigned int* qdet) {
    constexpr int TOT16 = (BM + BN) * 32;       // ushorts per buffer
    constexpr int CALLS = TOT16 / 512;          // 1KB chunks (16 rows x 32 cols)
    constexpr int CPW = CALLS / 4;
    constexpr int MT = BM / 32;                 // wave-tile (BM/2)x(BN/2)
    constexpr int NT = BN / 32;
    __shared__ unsigned short buf[2][TOT16];

    const int fl = detect_isb(qdet);
    const int t = threadIdx.x, lane = t & 63, w = t >> 6;
    const int lm = lane & 15, q4 = lane >> 4;
    const int wm = w >> 1, wn = w & 1;
    const int lr = lane >> 2;                    // row-in-chunk 0..15
    const int ls = lane & 3;                     // LDS slot 0..3
    const int lg = ls ^ ((lr >> 1) & 3);         // source granule (swizzle)

    const unsigned short* Abf;
    const unsigned short* Bt;
    const float* bias;
    int z = 0, m0, n0, phase;
    if (MODE == 0) {
        // grid (32,8,3); dispatch id -> XCD = id & 7 (round-robin)
        int bid = blockIdx.x + gridDim.x * (blockIdx.y + gridDim.y * blockIdx.z);
        int xcd = bid & 7, idx = bid >> 3;       // idx 0..95 within XCD
        z = idx >> 5;                            // 0..2 (sequential per XCD)
        int r = idx & 31;
        int mt = (xcd << 2) + (r & 3);           // XCD x owns m-tiles 4x..4x+3
        int nt = r >> 2;                         // 0..7
        m0 = mt * BM; n0 = nt * BN;
        phase = (nt * 13 + z * 5) & 31;          // same-B blocks K-aligned
        const void* Ain = (z == 0) ? A0 : (z == 1 ? A1 : A2);
        Abf = fl ? (const unsigned short*)Ain
                 : Aconv + (size_t)z * ((size_t)BS_ * D_);
        Bt = BtB + (size_t)z * D_ * D_;
        bias = biasB + z * 1024;
    } else {
        Abf = (const unsigned short*)A0;         // heads, always bf16
        Bt = BtB; bias = biasB;
        // grid (32,16): 512 blocks; xcd owns m-tiles [4x,4x+4) x all 16 nt
        int bid = blockIdx.x + (blockIdx.y << 5);
        int xcd = bid & 7, idx = bid >> 3;       // idx 0..63
        m0 = ((xcd << 2) + (idx & 3)) * BM;
        n0 = (idx >> 2) * BN;
        phase = ((idx >> 2) * 13) & 31;
    }

    // stage K-slice kk into buffer bi (swizzled: slot s of row r holds
    // global granule s ^ ((r>>1)&3)) — pure DMA, A and B both bf16
    auto stage = [&](int kk, int bi) {
#pragma unroll
        for (int i = 0; i < CPW; ++i) {
            int c = w * CPW + i;
            int row = c * 16 + lr;
            const unsigned short* g;
            if (row < BM)
                g = Abf + (size_t)(m0 + row) * D_ + kk + lg * 8;
            else
                g = Bt + (size_t)(n0 + row - BM) * D_ + kk + lg * 8;
            gl2lds16(g, &buf[bi][c * 512]);
        }
    };

    f32x4 acc[MT][NT];
#pragma unroll
    for (int i = 0; i < MT; i++)
#pragma unroll
        for (int j = 0; j < NT; j++) acc[i][j] = (f32x4){0.f, 0.f, 0.f, 0.f};

    stage((phase & 31) * 32, 0);
    for (int it = 0; it < D_ / 32; ++it) {
        const int bi = it & 1;
        __syncthreads();                 // drains the prefetch of slice `it`
        if (it < D_ / 32 - 1) stage(((it + 1 + phase) & 31) * 32, bi ^ 1);

        const unsigned short* As = buf[bi];
        const unsigned short* Bs = buf[bi] + BM * 32;
        bf16x8 af[MT], bv[NT];
#pragma unroll
        for (int mt = 0; mt < MT; mt++) {
            int row = wm * (BM / 2) + mt * 16 + lm;
            af[mt] = *(const bf16x8*)&As[row * 32 + (q4 ^ ((row >> 1) & 3)) * 8];
        }
#pragma unroll
        for (int nt = 0; nt < NT; nt++) {
            int row = wn * (BN / 2) + nt * 16 + lm;
            bv[nt] = *(const bf16x8*)&Bs[row * 32 + (q4 ^ ((row >> 1) & 3)) * 8];
        }
#pragma unroll
        for (int mt = 0; mt < MT; mt++)
#pragma unroll
            for (int nt = 0; nt < NT; nt++)
                acc[mt][nt] = __builtin_amdgcn_mfma_f32_16x16x32_bf16(
                    af[mt], bv[nt], acc[mt][nt], 0, 0, 0);
    }

    // epilogue: C/D layout col=lane&15, row=(lane>>4)*4+reg
#pragma unroll
    for (int mt = 0; mt < MT; mt++)
#pragma unroll
        for (int nt = 0; nt < NT; nt++) {
            int N = n0 + wn * (BN / 2) + nt * 16 + lm;
            int Mb = m0 + wm * (BM / 2) + mt * 16 + q4 * 4;
            if (MODE == 0 && z == 2) {
                // V^T: 4 consecutive s per lane -> one b64 store
                int bb = Mb >> 10, sb = Mb & 1023, hh = N >> 6, e = N & 63;
                unsigned long long hv = 0;
#pragma unroll
                for (int r = 0; r < 4; r++)
                    hv |= (unsigned long long)f2bf(acc[mt][nt][r] + bias[N]) << (16 * r);
                unsigned short* d16 = (unsigned short*)dstB + (size_t)2 * BHSE_;
                *(unsigned long long*)&d16[(((size_t)(bb * H_ + hh) * E_ + e) << 10) + sb] = hv;
            } else {
#pragma unroll
                for (int r = 0; r < 4; r++) {
                    int M = Mb + r;
                    float v = acc[mt][nt][r] + bias[N];
                    if (MODE == 0) {
                        int bb = M >> 10, s = M & 1023, hh = N >> 6, e = N & 63;
                        unsigned short* d16 = (unsigned short*)dstB + (size_t)z * BHSE_;
                        d16[((size_t)(bb * H_ + hh) * S_ + s) * E_ + e] = f2bf(v);
                    } else {
                        size_t idx = (size_t)M * D_ + N;
                        if (fl) ((unsigned short*)dstB)[idx] = f2bf(v);
                        else    ((float*)dstB)[idx] = v;
                    }
                }
            }
        }
}

// ---------------------------------------------------------------------------
// Kernel 4 (R12): fused attention. CHANGED vs R11:
//  (1) QBLK 64 -> 128: 512 threads / 8 waves per block, wave w owns q-rows
//      qt*128 + w*16 (per-wave structure identical). K/V tile staged once
//      per 128 q-rows (2 DMA chunks/wave instead of 4) -> half the staging
//      work & refetch. Grid (8,16,4) = 512 blocks = exactly 2/CU.
//  (2) XCD-aware remap: all 8 qt-blocks of one (h,b) land on ONE XCD
//      (xcd = hb&7 after remap) -> that XCD's 8 shared K/V sets (8 x 512KB
//      = 4MB) are L2-resident; K/V re-reads become L2 hits.
//  (3) mask word for tile kt+1 prefetched during tile kt (removes an
//      L2-latency stall from the per-iter critical path).
// ---------------------------------------------------------------------------
__global__ __launch_bounds__(512, 2) void attn64(
        const unsigned short* Qp, const unsigned short* Kp, const unsigned short* VpT,
        const unsigned long long* packT, unsigned short* heads) {
    __shared__ unsigned short KT[2][4096];   // [buf][64 keys x 64 e], swizzled
    __shared__ unsigned short VT[2][4096];   // [buf][64 e x 64 keys], swizzled

    // XCD remap: bid = qt + 8*hb (hb = h + 16*b); hw xcd = bid&7.
    // Give each xcd 8 full hb's: hb = xcd*8 + (idx&7), qt = idx>>3.
    const int bid = blockIdx.x + (blockIdx.y << 3) + (blockIdx.z << 7);
    const int xcd = bid & 7, idx = bid >> 3;
    const int qt = idx >> 3;
    const int hb = xcd * 8 + (idx & 7);
    const int h = hb & 15, b = hb >> 4;

    const int t = threadIdx.x, w = t >> 6, lane = t & 63, lm = lane & 15, q4 = lane >> 4;
    const size_t bh = ((size_t)b * H_ + h) * S_ * E_;
    const unsigned short* Qb = Qp + bh;
    const unsigned short* Kb = Kp + bh;
    const unsigned short* Vb = VpT + bh;                // Vb[e*1024 + s]
    const int q0 = qt * 128 + w * 16;

    // per-lane invariant DMA source offsets (ushort units)
    const int l3 = lane >> 3, l7 = lane & 7;
    const int kLaneOff = l3 * 64 + (l7 ^ l3) * 8;       // within an 8-row K chunk
    const int vLaneOff = l3 * 1024 + (l7 ^ l3) * 8;     // within an 8-row V chunk

    // swizzled LDS fragment chunk indices (granule = 8 ushorts)
    const int sw = lm & 7;
    const int c0 = (q4 ^ sw) * 8, c1 = ((q4 ^ 4) ^ sw) * 8;

    // bpermute source byte-addresses for the P redistribution
    const int srcA4 = ((lane & 15) | ((lane & 16) << 1)) << 2;  // (lm+(q4&1)*32)*4
    const int srcB4 = srcA4 + 64;                               // +16 lanes
    const bool selHi = (lane & 32) != 0;                        // q4 >= 2

    // Q B-fragments, held for the whole sweep
    bf16x8 bq0 = *(const bf16x8*)&Qb[(size_t)(q0 + lm) * E_ + q4 * 8];
    bf16x8 bq1 = *(const bf16x8*)&Qb[(size_t)(q0 + lm) * E_ + 32 + q4 * 8];

    f32x4 oacc[4];
#pragma unroll
    for (int i = 0; i < 4; i++) oacc[i] = (f32x4){0.f, 0.f, 0.f, 0.f};
    float mrun = -3.0e38f, lrun = 0.f;
    const float scale2 = 0.03125f * 1.4426950408889634f;   // log2e / sqrt(D)

// 16 chunks split over 8 waves: 2 DMA issues per wave per tile
#define STAGE(ktile, bufi)                                                    \
    {                                                                         \
        int k0s = (ktile) * 64;                                               \
        _Pragma("unroll")                                                     \
        for (int i_ = 0; i_ < 2; ++i_) {                                      \
            int c_ = w * 2 + i_;                                              \
            if (c_ < 8) {                                                     \
                gl2lds16(Kb + (size_t)k0s * 64 + c_ * 512 + kLaneOff,         \
                         &KT[bufi][c_ * 512]);                                \
            } else {                                                          \
                int cc_ = c_ - 8;                                             \
                gl2lds16(Vb + (size_t)cc_ * 8192 + k0s + vLaneOff,            \
                         &VT[bufi][cc_ * 512]);                               \
            }                                                                 \
        }                                                                     \
    }

    STAGE(0, 0)
    unsigned long long mk = packT[(size_t)b * 16 * 1024 + q0 + lm];

    for (int kt = 0; kt < S_ / 64; ++kt) {
        const int bufi = kt & 1;
        __syncthreads();                 // own-vmcnt drain + barrier: tile kt ready
        unsigned long long mknext = 0;
        if (kt < 15) {
            STAGE(kt + 1, bufi ^ 1)
            mknext = packT[((size_t)b * 16 + kt + 1) * 1024 + q0 + lm];
        }

        // Sc^T from LDS K tile
        f32x4 st[4];
#pragma unroll
        for (int jt = 0; jt < 4; ++jt) {
            const unsigned short* kr = &KT[bufi][(jt * 16 + lm) * 64];
            bf16x8 ka0 = *(const bf16x8*)&kr[c0];
            bf16x8 ka1 = *(const bf16x8*)&kr[c1];
            f32x4 zz = (f32x4){0.f, 0.f, 0.f, 0.f};
            zz = __builtin_amdgcn_mfma_f32_16x16x32_bf16(ka0, bq0, zz, 0, 0, 0);
            zz = __builtin_amdgcn_mfma_f32_16x16x32_bf16(ka1, bq1, zz, 0, 0, 0);
            st[jt] = zz;
        }

        // raw tile max, pairwise tree (masked entries: harmless overestimate)
        float mx0 = fmaxf(fmaxf(st[0][0], st[0][1]), fmaxf(st[0][2], st[0][3]));
        float mx1 = fmaxf(fmaxf(st[1][0], st[1][1]), fmaxf(st[1][2], st[1][3]));
        float mx2 = fmaxf(fmaxf(st[2][0], st[2][1]), fmaxf(st[2][2], st[2][3]));
        float mx3 = fmaxf(fmaxf(st[3][0], st[3][1]), fmaxf(st[3][2], st[3][3]));
        float tmx = fmaxf(fmaxf(mx0, mx1), fmaxf(mx2, mx3));
        tmx = fmaxf(tmx, __shfl_xor(tmx, 16, 64));
        tmx = fmaxf(tmx, __shfl_xor(tmx, 32, 64));
        float pmax = tmx * scale2;                 // per-q (lm) scaled tile max

        // defer-max: only rescale when some row's max grew past THR=8
        if (!__all(pmax - mrun <= 8.f)) {
            float mnew = fmaxf(mrun, pmax);
            float alpha = EXP2(mrun - mnew);
            lrun *= alpha;
#pragma unroll
            for (int nt = 0; nt < 4; nt++) oacc[nt] = oacc[nt] * alpha;
            mrun = mnew;
        }
        const float mneg = -mrun;

        // per-lane mask nibbles: jt0/1 bits in mn (r, 16+r), jt2/3 in mh
        unsigned int mn = (unsigned int)(mk >> (q4 * 4));
        unsigned int mh = (unsigned int)(mk >> (q4 * 4 + 32));

        float ssum = 0.f;
        unsigned int cl[8];                        // packed bf16 pairs
#pragma unroll
        for (int jt = 0; jt < 4; ++jt) {
            unsigned int mm = (jt & 2) ? mh : mn;
            const int sh = (jt & 1) * 16;
            float p0 = EXP2(fmaf(st[jt][0], scale2, mneg));
            float p1 = EXP2(fmaf(st[jt][1], scale2, mneg));
            float p2 = EXP2(fmaf(st[jt][2], scale2, mneg));
            float p3 = EXP2(fmaf(st[jt][3], scale2, mneg));
            p0 = (mm & (1u << (sh + 0))) ? p0 : 0.f;
            p1 = (mm & (1u << (sh + 1))) ? p1 : 0.f;
            p2 = (mm & (1u << (sh + 2))) ? p2 : 0.f;
            p3 = (mm & (1u << (sh + 3))) ? p3 : 0.f;
            ssum += (p0 + p1) + (p2 + p3);
            cl[jt * 2]     = cvtpk(p0, p1);
            cl[jt * 2 + 1] = cvtpk(p2, p3);
        }
        ssum += __shfl_xor(ssum, 16, 64);
        ssum += __shfl_xor(ssum, 32, 64);
        lrun += ssum;

        // in-register C->B redistribution:
        // bp0 word t holds k=q4*8+2t,+2t+1 for q=lm
        u32x4 w0, w1;
        {
            unsigned int aA0 = bperm(srcA4, cl[0]), aA2 = bperm(srcA4, cl[2]);
            unsigned int aA1 = bperm(srcA4, cl[1]), aA3 = bperm(srcA4, cl[3]);
            unsigned int aB0 = bperm(srcB4, cl[0]), aB2 = bperm(srcB4, cl[2]);
            unsigned int aB1 = bperm(srcB4, cl[1]), aB3 = bperm(srcB4, cl[3]);
            w0 = (u32x4){selHi ? aA2 : aA0, selHi ? aA3 : aA1,
                         selHi ? aB2 : aB0, selHi ? aB3 : aB1};
            unsigned int bA0 = bperm(srcA4, cl[4]), bA2 = bperm(srcA4, cl[6]);
            unsigned int bA1 = bperm(srcA4, cl[5]), bA3 = bperm(srcA4, cl[7]);
            unsigned int bB0 = bperm(srcB4, cl[4]), bB2 = bperm(srcB4, cl[6]);
            unsigned int bB1 = bperm(srcB4, cl[5]), bB3 = bperm(srcB4, cl[7]);
            w1 = (u32x4){selHi ? bA2 : bA0, selHi ? bA3 : bA1,
                         selHi ? bB2 : bB0, selHi ? bB3 : bB1};
        }
        bf16x8 bp0 = u4bf(w0);
        bf16x8 bp1 = u4bf(w1);

        // PV from LDS V tile
#pragma unroll
        for (int nt = 0; nt < 4; nt++) {
            const unsigned short* vr = &VT[bufi][(nt * 16 + lm) * 64];
            bf16x8 va0 = *(const bf16x8*)&vr[c0];
            bf16x8 va1 = *(const bf16x8*)&vr[c1];
            oacc[nt] = __builtin_amdgcn_mfma_f32_16x16x32_bf16(va0, bp0, oacc[nt], 0, 0, 0);
            oacc[nt] = __builtin_amdgcn_mfma_f32_16x16x32_bf16(va1, bp1, oacc[nt], 0, 0, 0);
        }
        mk = mknext;
    }

    float inv = 1.0f / lrun;
#pragma unroll
    for (int nt = 0; nt < 4; nt++) {
        unsigned int lo = cvtpk(oacc[nt][0] * inv, oacc[nt][1] * inv);
        unsigned int hi = cvtpk(oacc[nt][2] * inv, oacc[nt][3] * inv);
        unsigned long long hv = (unsigned long long)lo | ((unsigned long long)hi << 32);
        *(unsigned long long*)&heads[(size_t)(b * S_ + q0 + lm) * D_ + h * E_ + nt * 16 + q4 * 4] = hv;
    }
}

// ---------------------------------------------------------------------------
extern "C" void kernel_launch(void* const* d_in, const int* in_sizes, int n_in,
                              void* d_out, int out_size, void* d_ws, size_t ws_size,
                              hipStream_t stream) {
    char* ws = (char*)d_ws;
    unsigned short* WT = (unsigned short*)(ws + 256);    // [4][1024][1024] bf16
    unsigned short* WqT = WT;
    unsigned short* WoT = WT + (size_t)3 * D_ * D_;
    float* biases = (float*)(WT + (size_t)4 * D_ * D_);  // [4][1024]
    float* bq = biases;
    float* bo = biases + 3 * 1024;
    unsigned short* Qp = (unsigned short*)(biases + 4 * 1024);  // [b][h][s][e]
    unsigned short* Kp = Qp + (size_t)BHSE_;                    // [b][h][s][e]
    unsigned short* Vp = Kp + (size_t)BHSE_;                    // [b][h][e][s]
    unsigned short* heads = Vp + (size_t)BHSE_;                 // [b*s][h*64+e]
    unsigned long long* packT = (unsigned long long*)(heads + (size_t)BHSE_);
    unsigned short* Aconv = (unsigned short*)(packT + (size_t)B_ * 16 * S_); // [3][4096][1024] bf16

    // merged preprocessing: weights + bias, mask bitpack, A fp32->bf16
    preproc<<<11264, 256, 0, stream>>>(
        d_in[0], d_in[1], d_in[2], (const int*)d_in[3],
        d_in[4], d_in[6], d_in[8], d_in[10],
        d_in[5], d_in[7], d_in[9], d_in[11],
        WT, biases, packT, Aconv);
    // proj: 128x128 tiles -> 32 x 8 x 3 = 768 blocks (3/CU), XCD m-stripes
    gemm_k<128, 128, 0, 3><<<dim3(32, 8, 3), 256, 0, stream>>>(
        d_in[0], d_in[1], d_in[2], Aconv, WqT, bq, Qp,
        (const unsigned int*)d_in[0]);
    // attn: QBLK=128, 8 waves/block -> 8 x 16 x 4 = 512 blocks (2/CU),
    // (h,b)-clustered per XCD
    attn64<<<dim3(8, 16, 4), 512, 0, stream>>>(Qp, Kp, Vp, packT, heads);
    // final: 128x64 tiles -> 32 x 16 = 512 blocks, XCD m-stripes
    gemm_k<128, 64, 1, 4><<<dim3(32, 16, 1), 256, 0, stream>>>(
        heads, nullptr, nullptr, nullptr, WoT, bo, d_out,
        (const unsigned int*)d_in[0]);
}